// Round 7
// baseline (804.952 us; speedup 1.0000x reference)
//
#include <hip/hip_runtime.h>
#include <hip/hip_fp16.h>

typedef _Float16 half_t;
typedef _Float16 f16x8 __attribute__((ext_vector_type(8)));
typedef _Float16 f16x4 __attribute__((ext_vector_type(4)));
typedef float f32x4 __attribute__((ext_vector_type(4)));

// problem constants
#define NB   16
#define CD   640
#define HWD  4096
#define TT   77
#define CTXD 768
#define NH   8
#define DH   80
#define DP   96   // padded d / padded T for the attention kernel

#define GLOAD16(gp, lp)                                                        \
  __builtin_amdgcn_global_load_lds(                                            \
      (const __attribute__((address_space(1))) void*)(gp),                     \
      (__attribute__((address_space(3))) void*)(lp), 16, 0, 0)

// XCD-locality swizzle: 5 n-blocks of one 256-row m-panel -> same XCD.
// grid = 1280 = 8 XCD * 160 slots; 256 panels (%8==0) -> bijective.
__device__ inline void xcd_panel_map(int j, int& panel, int& nblk) {
  const int xcd = j & 7, slot = j >> 3;
  panel = (slot / 5) * 8 + xcd;
  nblk = slot % 5;
}

// ---------------- x transpose + f32->f16 convert ----------------
// x (B, 640, 4096) f32 -> xt (B, 4096, 640) f16
__global__ __launch_bounds__(256) void xpose_kernel(
    const float* __restrict__ x, half_t* __restrict__ xt) {
  __shared__ half_t tile[64][72];
  const float* s = x + (long)blockIdx.z * CD * HWD;
  half_t* d = xt + (long)blockIdx.z * HWD * CD;
  const int r0 = blockIdx.y * 64;   // channel
  const int c0 = blockIdx.x * 64;   // pixel
  const int t = threadIdx.x;
  const int rr = t >> 4, cc = (t & 15) * 4;
#pragma unroll
  for (int j = 0; j < 4; ++j) {
    const int r = rr + j * 16;
    float4 v = *reinterpret_cast<const float4*>(&s[(long)(r0 + r) * HWD + c0 + cc]);
    tile[cc + 0][r] = (half_t)v.x;
    tile[cc + 1][r] = (half_t)v.y;
    tile[cc + 2][r] = (half_t)v.z;
    tile[cc + 3][r] = (half_t)v.w;
  }
  __syncthreads();
  const int cr = t >> 2, rc = (t & 3) * 16;
  half_t* dp = &d[(long)(c0 + cr) * CD + r0 + rc];
  *reinterpret_cast<int4*>(dp)     = *reinterpret_cast<const int4*>(&tile[cr][rc]);
  *reinterpret_cast<int4*>(dp + 8) = *reinterpret_cast<const int4*>(&tile[cr][rc + 8]);
}

// ---------------- merged weight transpose + f32->f16 convert ----------------
__global__ __launch_bounds__(256) void wtrans_kernel(
    const float* __restrict__ Wq, const float* __restrict__ Wk,
    const float* __restrict__ Wv, const float* __restrict__ Wo,
    half_t* __restrict__ WqT, half_t* __restrict__ WkT,
    half_t* __restrict__ WvT, half_t* __restrict__ WoT) {
  __shared__ half_t tile[64][72];
  const int z = blockIdx.z;
  const float* src = (z == 0) ? Wq : (z == 1) ? Wk : (z == 2) ? Wv : Wo;
  half_t* dst      = (z == 0) ? WqT : (z == 1) ? WkT : (z == 2) ? WvT : WoT;
  const int R = (z == 1 || z == 2) ? CTXD : CD;
  const int r0 = blockIdx.y * 64, c0 = blockIdx.x * 64;
  if (r0 >= R) return;
  const int t = threadIdx.x;
  const int rr = t >> 4, cc = (t & 15) * 4;
#pragma unroll
  for (int j = 0; j < 4; ++j) {
    const int r = rr + j * 16;
    float4 v = *reinterpret_cast<const float4*>(&src[(long)(r0 + r) * CD + c0 + cc]);
    tile[cc + 0][r] = (half_t)v.x;
    tile[cc + 1][r] = (half_t)v.y;
    tile[cc + 2][r] = (half_t)v.z;
    tile[cc + 3][r] = (half_t)v.w;
  }
  __syncthreads();
  const int cr = t >> 2, rc = (t & 3) * 16;
  half_t* dp = &dst[(long)(c0 + cr) * R + r0 + rc];
  *reinterpret_cast<int4*>(dp)     = *reinterpret_cast<const int4*>(&tile[cr][rc]);
  *reinterpret_cast<int4*>(dp + 8) = *reinterpret_cast<const int4*>(&tile[cr][rc + 8]);
}

// ---------------- K/V projection ----------------
// ctx (B,77,768) f32 @ WT(640,768)^T + bias ->
//   kv==0: k_ws  (B, 8, 80, 96)  [t][dd]
//   kv==1: vT_ws (B, 8, 80, 96)  [dd][t]
// Pad columns [80,96) zeroed here (block x==0 of each (b,kv)).
__global__ __launch_bounds__(256) void kv_kernel(
    const float* __restrict__ ctx,
    const half_t* __restrict__ WkT, const half_t* __restrict__ WvT,
    const float* __restrict__ bk, const float* __restrict__ bv,
    half_t* __restrict__ k_ws, half_t* __restrict__ vT_ws) {
  __shared__ half_t C_sm[80][32];
  const int n0 = blockIdx.x * 64;
  const int b  = blockIdx.y;
  const int kv = blockIdx.z;
  const half_t* WT  = kv ? WvT : WkT;
  const float* bias = kv ? bv : bk;
  const int tid = threadIdx.x;
  const int wave = tid >> 6, lane = tid & 63, g = lane >> 4, ln = lane & 15;

  if (blockIdx.x == 0) {
    half_t* dst = kv ? vT_ws : k_ws;
    for (int i = tid; i < 1280; i += 256) {   // 8h * 80rows * 2 chunks
      const int hh = i / 160, rr = i % 160;
      half_t* p = dst + (((long)b * NH + hh) * 80 + (rr >> 1)) * DP + 80 + (rr & 1) * 8;
      *reinterpret_cast<int4*>(p) = make_int4(0, 0, 0, 0);
    }
  }

  f32x4 acc[5];
#pragma unroll
  for (int i = 0; i < 5; ++i) acc[i] = (f32x4){0.f, 0.f, 0.f, 0.f};

  for (int k0 = 0; k0 < CTXD; k0 += 32) {
    if (k0) __syncthreads();
    for (int i = tid; i < 320; i += 256) {
      const int r = i >> 2, c8 = (i & 3) * 8;
      f16x8 hv = {0, 0, 0, 0, 0, 0, 0, 0};
      if (r < TT) {
        const float* cp = ctx + ((long)b * TT + r) * CTXD + k0 + c8;
        float4 c0v = *reinterpret_cast<const float4*>(cp);
        float4 c1v = *reinterpret_cast<const float4*>(cp + 4);
        hv[0] = (half_t)c0v.x; hv[1] = (half_t)c0v.y;
        hv[2] = (half_t)c0v.z; hv[3] = (half_t)c0v.w;
        hv[4] = (half_t)c1v.x; hv[5] = (half_t)c1v.y;
        hv[6] = (half_t)c1v.z; hv[7] = (half_t)c1v.w;
      }
      *reinterpret_cast<f16x8*>(&C_sm[r][c8]) = hv;
    }
    __syncthreads();
    f16x8 bfr = *reinterpret_cast<const f16x8*>(
        &WT[(long)(n0 + wave * 16 + ln) * CTXD + k0 + g * 8]);
#pragma unroll
    for (int mt = 0; mt < 5; ++mt) {
      f16x8 afr = *reinterpret_cast<const f16x8*>(&C_sm[mt * 16 + ln][g * 8]);
      acc[mt] = __builtin_amdgcn_mfma_f32_16x16x32_f16(afr, bfr, acc[mt], 0, 0, 0);
    }
  }

  const int n = n0 + wave * 16 + ln;
  const float bsv = bias[n];
  const int h = n / DH, dd = n % DH;
  if (kv == 0) {
#pragma unroll
    for (int mt = 0; mt < 5; ++mt)
#pragma unroll
      for (int r = 0; r < 4; ++r) {
        const int t = mt * 16 + g * 4 + r;
        k_ws[(((long)b * NH + h) * 80 + t) * DP + dd] = (half_t)(acc[mt][r] + bsv);
      }
  } else {
#pragma unroll
    for (int mt = 0; mt < 5; ++mt) {
      const int t0 = mt * 16 + g * 4;
      f16x4 v4;
#pragma unroll
      for (int r = 0; r < 4; ++r) v4[r] = (half_t)(acc[mt][r] + bsv);
      *reinterpret_cast<f16x4*>(&vT_ws[(((long)b * NH + h) * 80 + dd) * DP + t0]) = v4;
    }
  }
}

// ---------------- panel GEMM, 256x128, DOUBLE-BUFFER phase-split ------------
// Round-7 A/B vs round-5's triple-buffer 2-ahead (96 us, 72 KB, 2 blk/CU):
// 2 LDS buffers (48 KB) -> 3 blocks/CU (24 waves) for +50% TLP; 1-ahead
// pipeline: both A+B stages for (t+1) issue in phase 1, drained by ONE
// vmcnt(0) at step end (T4 traded for occupancy -- the drain has a
// ~full-step latency window and 24 waves of cover). 3 barriers/step.
// Buffer safety: stage(t+1) -> buf[cur^1], last read step t-1, fenced by
// step t-1's closing barrier; step-end barrier (all waves past vmcnt(0))
// publishes buf[cur^1] for step t+1's reads.
template <int EPI>
__global__ __launch_bounds__(512, 6) void pgemm8_kernel(
    const half_t* __restrict__ A, const half_t* __restrict__ BT,
    const float* __restrict__ bias, void* __restrict__ outp) {
  __shared__ __align__(16) half_t A_sm[2][256 * 32];   // 32 KB
  __shared__ __align__(16) half_t B_sm[2][128 * 32];   // 16 KB
  const int tid = threadIdx.x;
  const int lane = tid & 63, wave = tid >> 6;   // wave 0..7
  const int g = lane >> 4, ln = lane & 15;
  const int wm = wave >> 1, wn = wave & 1;      // 4 x 2 wave grid

  int panel, nblk;
  xcd_panel_map(blockIdx.x, panel, nblk);
  const long m0 = (long)panel * 256;
  const int n0 = nblk * 128;

  // staging map (proven 0-conflict rounds 0-6)
  const int srow = tid >> 2;                                  // 0..127
  const int sk8 = ((tid & 3) ^ ((tid >> 3) & 3)) * 8;
  const half_t* ag0 = A + (m0 + srow) * CD + sk8;
  const half_t* ag1 = ag0 + 128 * CD;                         // rows 128..255
  const half_t* bg0 = BT + (long)(n0 + srow) * CD + sk8;

  // fragment-read slot (loop-invariant): g ^ ((ln>>1)&3)
  const int rs8 = (g ^ ((ln >> 1) & 3)) * 8;

  f32x4 acc[4][4];
#pragma unroll
  for (int i = 0; i < 4; ++i)
#pragma unroll
    for (int j = 0; j < 4; ++j) acc[i][j] = (f32x4){0.f, 0.f, 0.f, 0.f};

#define STAGE_AB(buf, kt)                                             \
  do {                                                                \
    GLOAD16(ag0 + (long)(kt) * 32, &A_sm[buf][wave * 512]);           \
    GLOAD16(ag1 + (long)(kt) * 32, &A_sm[buf][4096 + wave * 512]);    \
    GLOAD16(bg0 + (long)(kt) * 32, &B_sm[buf][wave * 512]);           \
  } while (0)

#define READ_A2(dst0, dst1, buf, mi0)                                 \
  do {                                                                \
    dst0 = *reinterpret_cast<const f16x8*>(                           \
        &A_sm[buf][(wm * 64 + (mi0) * 16 + ln) * 32 + rs8]);          \
    dst1 = *reinterpret_cast<const f16x8*>(                           \
        &A_sm[buf][(wm * 64 + ((mi0) + 1) * 16 + ln) * 32 + rs8]);    \
  } while (0)
#define READ_B4(bf, buf)                                              \
  do {                                                                \
    _Pragma("unroll")                                                 \
    for (int ni = 0; ni < 4; ++ni)                                    \
      bf[ni] = *reinterpret_cast<const f16x8*>(                       \
          &B_sm[buf][(wn * 64 + ni * 16 + ln) * 32 + rs8]);           \
  } while (0)

#define MFMA8(a0, a1, bf, mi0)                                        \
  do {                                                                \
    __builtin_amdgcn_s_setprio(1);                                    \
    _Pragma("unroll")                                                 \
    for (int ni = 0; ni < 4; ++ni)                                    \
      acc[mi0][ni] = __builtin_amdgcn_mfma_f32_16x16x32_f16(          \
          a0, bf[ni], acc[mi0][ni], 0, 0, 0);                         \
    _Pragma("unroll")                                                 \
    for (int ni = 0; ni < 4; ++ni)                                    \
      acc[(mi0) + 1][ni] = __builtin_amdgcn_mfma_f32_16x16x32_f16(    \
          a1, bf[ni], acc[(mi0) + 1][ni], 0, 0, 0);                   \
    __builtin_amdgcn_s_setprio(0);                                    \
  } while (0)

#define WAIT_LGKM_FENCE()                                             \
  do {                                                                \
    asm volatile("s_waitcnt lgkmcnt(0)" ::: "memory");                \
    __builtin_amdgcn_sched_barrier(0);                                \
  } while (0)

  // prologue: stage(0), drain, publish
  STAGE_AB(0, 0);
  asm volatile("s_waitcnt vmcnt(0)" ::: "memory");
  __builtin_amdgcn_s_barrier();

  const int nk = CD / 32;  // 20
  f16x8 a0, a1, a2, a3, bf[4];
  for (int t = 0; t < nk; ++t) {
    const int cur = t & 1, nxt = cur ^ 1;
    // ---- phase 1: reads + full stage(t+1) issue, 8 MFMA (mi 0,1) ----
    READ_A2(a0, a1, cur, 0);
    READ_B4(bf, cur);
    if (t + 1 < nk) STAGE_AB(nxt, t + 1);
    __builtin_amdgcn_s_barrier();
    WAIT_LGKM_FENCE();
    MFMA8(a0, a1, bf, 0);
    __builtin_amdgcn_s_barrier();
    // ---- phase 2: wave-private reads, 8 MFMA (mi 2,3), step-end drain ----
    READ_A2(a2, a3, cur, 2);
    WAIT_LGKM_FENCE();
    MFMA8(a2, a3, bf, 2);
    if (t + 1 < nk) {
      asm volatile("s_waitcnt vmcnt(0)" ::: "memory");   // stage(t+1) landed
      __builtin_amdgcn_s_barrier();                      // publish buf[nxt]
    }
  }

  if (EPI == 0) {
    half_t* O = (half_t*)outp;
#pragma unroll
    for (int ni = 0; ni < 4; ++ni) {
      const int n = n0 + wn * 64 + ni * 16 + ln;
      const float bvv = bias[n];
#pragma unroll
      for (int mi = 0; mi < 4; ++mi) {
        const long m = m0 + wm * 64 + mi * 16 + g * 4;
        f32x4 v = acc[mi][ni];
#pragma unroll
        for (int r = 0; r < 4; ++r)
          O[(m + r) * CD + n] = (half_t)(v[r] + bvv);
      }
    }
  } else {
    float* O = (float*)outp;
#pragma unroll
    for (int mi = 0; mi < 4; ++mi) {
      const long m = m0 + wm * 64 + mi * 16 + g * 4;
      const long bb = m >> 12;
      const int p = (int)(m & 4095);
#pragma unroll
      for (int ni = 0; ni < 4; ++ni) {
        const int n = n0 + wn * 64 + ni * 16 + ln;
        const float bvv = bias[n];
        f32x4 v = acc[mi][ni];
        float4 o4 = make_float4(v[0] + bvv, v[1] + bvv, v[2] + bvv, v[3] + bvv);
        *reinterpret_cast<float4*>(&O[((bb * CD + n) << 12) + p]) = o4;
      }
    }
  }
#undef STAGE_AB
#undef READ_A2
#undef READ_B4
#undef MFMA8
#undef WAIT_LGKM_FENCE
}

// ---------------- fused attention (128 px / block, 512 threads) -------------
__global__ __launch_bounds__(512) void attn_kernel(
    const half_t* __restrict__ q_ws, const half_t* __restrict__ k_ws,
    const half_t* __restrict__ vT_ws, half_t* __restrict__ attn_ws) {
  __shared__ half_t K_sm[80][DP];
  __shared__ half_t V_sm[80][DP];
  __shared__ half_t Q_sm[128][DP];  // becomes P after softmax (pads stay 0)
  const int p0 = blockIdx.x * 128;
  const int h  = blockIdx.y;
  const int b  = blockIdx.z;
  const int tid = threadIdx.x, wave = tid >> 6, lane = tid & 63;
  const int g = lane >> 4, ln = lane & 15;

  const half_t* kp = k_ws  + ((long)b * NH + h) * 80 * DP;
  const half_t* vp = vT_ws + ((long)b * NH + h) * 80 * DP;
  for (int i = tid; i < 960; i += 512) {   // 80*96/8 int4 chunks
    reinterpret_cast<int4*>(K_sm)[i] = reinterpret_cast<const int4*>(kp)[i];
    reinterpret_cast<int4*>(V_sm)[i] = reinterpret_cast<const int4*>(vp)[i];
  }
  for (int i = tid; i < 1536; i += 512) {  // 128 rows x 12 chunks
    const int r = i / 12, c8 = i % 12;
    int4 v = make_int4(0, 0, 0, 0);
    if (c8 < 10)
      v = *reinterpret_cast<const int4*>(
          q_ws + ((long)(b * HWD + p0 + r)) * CD + h * DH + c8 * 8);
    *reinterpret_cast<int4*>(&Q_sm[r][c8 * 8]) = v;
  }
  __syncthreads();

  // S^T = K(80x96) @ Q^T(96x16)
  f32x4 s[5];
#pragma unroll
  for (int i = 0; i < 5; ++i) s[i] = (f32x4){0.f, 0.f, 0.f, 0.f};
#pragma unroll
  for (int ks = 0; ks < 3; ++ks) {
    f16x8 bq = *reinterpret_cast<const f16x8*>(&Q_sm[wave * 16 + ln][ks * 32 + g * 8]);
#pragma unroll
    for (int mt = 0; mt < 5; ++mt) {
      f16x8 ak = *reinterpret_cast<const f16x8*>(&K_sm[mt * 16 + ln][ks * 32 + g * 8]);
      s[mt] = __builtin_amdgcn_mfma_f32_16x16x32_f16(ak, bq, s[mt], 0, 0, 0);
    }
  }

  // masked softmax over t (valid t<77)
  const float sc = 0.11180339887498949f;   // 80^-0.5
  float mx = -1e30f;
#pragma unroll
  for (int mt = 0; mt < 5; ++mt)
#pragma unroll
    for (int r = 0; r < 4; ++r) {
      const int t = mt * 16 + g * 4 + r;
      const float v = s[mt][r] * sc;
      s[mt][r] = v;
      if (t < TT) mx = fmaxf(mx, v);
    }
  mx = fmaxf(mx, __shfl_xor(mx, 16));
  mx = fmaxf(mx, __shfl_xor(mx, 32));
  float e[5][4];
  float sum = 0.f;
#pragma unroll
  for (int mt = 0; mt < 5; ++mt)
#pragma unroll
    for (int r = 0; r < 4; ++r) {
      const int t = mt * 16 + g * 4 + r;
      float ev = 0.f;
      if (t < TT) { ev = __expf(s[mt][r] - mx); sum += ev; }
      e[mt][r] = ev;
    }
  sum += __shfl_xor(sum, 16);
  sum += __shfl_xor(sum, 32);
  const float inv = 1.f / sum;
#pragma unroll
  for (int mt = 0; mt < 5; ++mt) {
    f16x4 pv;
#pragma unroll
    for (int r = 0; r < 4; ++r) pv[r] = (half_t)(e[mt][r] * inv);
    *reinterpret_cast<f16x4*>(&Q_sm[wave * 16 + ln][mt * 16 + g * 4]) = pv;
  }

  // O^T = V^T(80x96) @ P(96x16)
  f32x4 o[5];
#pragma unroll
  for (int i = 0; i < 5; ++i) o[i] = (f32x4){0.f, 0.f, 0.f, 0.f};
#pragma unroll
  for (int ks = 0; ks < 3; ++ks) {
    f16x8 bp = *reinterpret_cast<const f16x8*>(&Q_sm[wave * 16 + ln][ks * 32 + g * 8]);
#pragma unroll
    for (int mt = 0; mt < 5; ++mt) {
      f16x8 av = *reinterpret_cast<const f16x8*>(&V_sm[mt * 16 + ln][ks * 32 + g * 8]);
      o[mt] = __builtin_amdgcn_mfma_f32_16x16x32_f16(av, bp, o[mt], 0, 0, 0);
    }
  }

  half_t* op = attn_ws + ((long)(b * HWD + p0 + wave * 16 + ln)) * CD + h * DH;
#pragma unroll
  for (int mt = 0; mt < 5; ++mt) {
    f16x4 v4;
#pragma unroll
    for (int r = 0; r < 4; ++r) v4[r] = (half_t)o[mt][r];
    *reinterpret_cast<f16x4*>(&op[mt * 16 + g * 4]) = v4;
  }
}

// ---------------- launch ----------------
extern "C" void kernel_launch(void* const* d_in, const int* in_sizes, int n_in,
                              void* d_out, int out_size, void* d_ws, size_t ws_size,
                              hipStream_t stream) {
  const float* x   = (const float*)d_in[0];
  const float* ctx = (const float*)d_in[1];
  const float* Wq  = (const float*)d_in[2];
  const float* bq  = (const float*)d_in[3];
  const float* Wk  = (const float*)d_in[4];
  const float* bk  = (const float*)d_in[5];
  const float* Wv  = (const float*)d_in[6];
  const float* bv  = (const float*)d_in[7];
  const float* Wo  = (const float*)d_in[8];
  const float* bo  = (const float*)d_in[9];
  float* out = (float*)d_out;

  char* ws = (char*)d_ws;
  size_t off = 0;
  auto alloc = [&](size_t bytes) {
    void* p = ws + off;
    off += (bytes + 255) & ~(size_t)255;
    return p;
  };
  half_t* WqT  = (half_t*)alloc((size_t)CD * CD * 2);
  half_t* WkT  = (half_t*)alloc((size_t)CD * CTXD * 2);
  half_t* WvT  = (half_t*)alloc((size_t)CD * CTXD * 2);
  half_t* WoT  = (half_t*)alloc((size_t)CD * CD * 2);
  half_t* kws  = (half_t*)alloc((size_t)NB * NH * 80 * DP * 2);
  half_t* vTws = (half_t*)alloc((size_t)NB * NH * 80 * DP * 2);
  half_t* xt   = (half_t*)alloc((size_t)NB * HWD * CD * 2);
  half_t* q    = (half_t*)alloc((size_t)NB * HWD * CD * 2);
  half_t* attn = xt;   // xt dead after pgemm8<0>; alias

  // weight transposes (f32 -> f16)
  wtrans_kernel<<<dim3(CD / 64, CTXD / 64, 4), 256, 0, stream>>>(
      Wq, Wk, Wv, Wo, WqT, WkT, WvT, WoT);

  // K/V projection (+ pad zeroing)
  kv_kernel<<<dim3(CD / 64, NB, 2), 256, 0, stream>>>(ctx, WkT, WvT, bk, bv, kws, vTws);

  // x transpose + convert
  xpose_kernel<<<dim3(HWD / 64, CD / 64, NB), 256, 0, stream>>>(x, xt);

  // Q projection (256x128 tiles, double-buffer phase-split, 3 blk/CU)
  pgemm8_kernel<0><<<(CD / 128) * ((NB * HWD) / 256), 512, 0, stream>>>(
      xt, WqT, bq, q);

  // fused attention (128 px / block)
  attn_kernel<<<dim3(HWD / 128, NH, NB), 512, 0, stream>>>(q, kws, vTws, attn);

  // O projection (256x128 tiles, double-buffer phase-split, 3 blk/CU)
  pgemm8_kernel<1><<<(CD / 128) * ((NB * HWD) / 256), 512, 0, stream>>>(
      attn, WoT, bo, out);
}

// Round 8
// 309.460 us; speedup vs baseline: 2.6012x; 2.6012x over previous
//
#include <hip/hip_runtime.h>
#include <hip/hip_fp16.h>

typedef _Float16 half_t;
typedef _Float16 f16x8 __attribute__((ext_vector_type(8)));
typedef _Float16 f16x4 __attribute__((ext_vector_type(4)));
typedef float f32x4 __attribute__((ext_vector_type(4)));

// problem constants
#define NB   16
#define CD   640
#define HWD  4096
#define TT   77
#define CTXD 768
#define NH   8
#define DH   80
#define DP   96   // padded d / padded T for the attention kernel

#define GLOAD16(gp, lp)                                                        \
  __builtin_amdgcn_global_load_lds(                                            \
      (const __attribute__((address_space(1))) void*)(gp),                     \
      (__attribute__((address_space(3))) void*)(lp), 16, 0, 0)

// XCD-locality swizzle: 5 n-blocks of one 256-row m-panel -> same XCD.
// grid = 1280 = 8 XCD * 160 slots; 256 panels (%8==0) -> bijective.
__device__ inline void xcd_panel_map(int j, int& panel, int& nblk) {
  const int xcd = j & 7, slot = j >> 3;
  panel = (slot / 5) * 8 + xcd;
  nblk = slot % 5;
}

// ---------------- x transpose + f32->f16 convert ----------------
// x (B, 640, 4096) f32 -> xt (B, 4096, 640) f16
__global__ __launch_bounds__(256) void xpose_kernel(
    const float* __restrict__ x, half_t* __restrict__ xt) {
  __shared__ half_t tile[64][72];
  const float* s = x + (long)blockIdx.z * CD * HWD;
  half_t* d = xt + (long)blockIdx.z * HWD * CD;
  const int r0 = blockIdx.y * 64;   // channel
  const int c0 = blockIdx.x * 64;   // pixel
  const int t = threadIdx.x;
  const int rr = t >> 4, cc = (t & 15) * 4;
#pragma unroll
  for (int j = 0; j < 4; ++j) {
    const int r = rr + j * 16;
    float4 v = *reinterpret_cast<const float4*>(&s[(long)(r0 + r) * HWD + c0 + cc]);
    tile[cc + 0][r] = (half_t)v.x;
    tile[cc + 1][r] = (half_t)v.y;
    tile[cc + 2][r] = (half_t)v.z;
    tile[cc + 3][r] = (half_t)v.w;
  }
  __syncthreads();
  const int cr = t >> 2, rc = (t & 3) * 16;
  half_t* dp = &d[(long)(c0 + cr) * CD + r0 + rc];
  *reinterpret_cast<int4*>(dp)     = *reinterpret_cast<const int4*>(&tile[cr][rc]);
  *reinterpret_cast<int4*>(dp + 8) = *reinterpret_cast<const int4*>(&tile[cr][rc + 8]);
}

// ---------------- merged weight transpose + f32->f16 convert ----------------
__global__ __launch_bounds__(256) void wtrans_kernel(
    const float* __restrict__ Wq, const float* __restrict__ Wk,
    const float* __restrict__ Wv, const float* __restrict__ Wo,
    half_t* __restrict__ WqT, half_t* __restrict__ WkT,
    half_t* __restrict__ WvT, half_t* __restrict__ WoT) {
  __shared__ half_t tile[64][72];
  const int z = blockIdx.z;
  const float* src = (z == 0) ? Wq : (z == 1) ? Wk : (z == 2) ? Wv : Wo;
  half_t* dst      = (z == 0) ? WqT : (z == 1) ? WkT : (z == 2) ? WvT : WoT;
  const int R = (z == 1 || z == 2) ? CTXD : CD;
  const int r0 = blockIdx.y * 64, c0 = blockIdx.x * 64;
  if (r0 >= R) return;
  const int t = threadIdx.x;
  const int rr = t >> 4, cc = (t & 15) * 4;
#pragma unroll
  for (int j = 0; j < 4; ++j) {
    const int r = rr + j * 16;
    float4 v = *reinterpret_cast<const float4*>(&src[(long)(r0 + r) * CD + c0 + cc]);
    tile[cc + 0][r] = (half_t)v.x;
    tile[cc + 1][r] = (half_t)v.y;
    tile[cc + 2][r] = (half_t)v.z;
    tile[cc + 3][r] = (half_t)v.w;
  }
  __syncthreads();
  const int cr = t >> 2, rc = (t & 3) * 16;
  half_t* dp = &dst[(long)(c0 + cr) * R + r0 + rc];
  *reinterpret_cast<int4*>(dp)     = *reinterpret_cast<const int4*>(&tile[cr][rc]);
  *reinterpret_cast<int4*>(dp + 8) = *reinterpret_cast<const int4*>(&tile[cr][rc + 8]);
}

// ---------------- K/V projection ----------------
// ctx (B,77,768) f32 @ WT(640,768)^T + bias ->
//   kv==0: k_ws  (B, 8, 80, 96)  [t][dd]
//   kv==1: vT_ws (B, 8, 80, 96)  [dd][t]
// Pad columns [80,96) zeroed here (block x==0 of each (b,kv)).
__global__ __launch_bounds__(256) void kv_kernel(
    const float* __restrict__ ctx,
    const half_t* __restrict__ WkT, const half_t* __restrict__ WvT,
    const float* __restrict__ bk, const float* __restrict__ bv,
    half_t* __restrict__ k_ws, half_t* __restrict__ vT_ws) {
  __shared__ half_t C_sm[80][32];
  const int n0 = blockIdx.x * 64;
  const int b  = blockIdx.y;
  const int kv = blockIdx.z;
  const half_t* WT  = kv ? WvT : WkT;
  const float* bias = kv ? bv : bk;
  const int tid = threadIdx.x;
  const int wave = tid >> 6, lane = tid & 63, g = lane >> 4, ln = lane & 15;

  if (blockIdx.x == 0) {
    half_t* dst = kv ? vT_ws : k_ws;
    for (int i = tid; i < 1280; i += 256) {   // 8h * 80rows * 2 chunks
      const int hh = i / 160, rr = i % 160;
      half_t* p = dst + (((long)b * NH + hh) * 80 + (rr >> 1)) * DP + 80 + (rr & 1) * 8;
      *reinterpret_cast<int4*>(p) = make_int4(0, 0, 0, 0);
    }
  }

  f32x4 acc[5];
#pragma unroll
  for (int i = 0; i < 5; ++i) acc[i] = (f32x4){0.f, 0.f, 0.f, 0.f};

  for (int k0 = 0; k0 < CTXD; k0 += 32) {
    if (k0) __syncthreads();
    for (int i = tid; i < 320; i += 256) {
      const int r = i >> 2, c8 = (i & 3) * 8;
      f16x8 hv = {0, 0, 0, 0, 0, 0, 0, 0};
      if (r < TT) {
        const float* cp = ctx + ((long)b * TT + r) * CTXD + k0 + c8;
        float4 c0v = *reinterpret_cast<const float4*>(cp);
        float4 c1v = *reinterpret_cast<const float4*>(cp + 4);
        hv[0] = (half_t)c0v.x; hv[1] = (half_t)c0v.y;
        hv[2] = (half_t)c0v.z; hv[3] = (half_t)c0v.w;
        hv[4] = (half_t)c1v.x; hv[5] = (half_t)c1v.y;
        hv[6] = (half_t)c1v.z; hv[7] = (half_t)c1v.w;
      }
      *reinterpret_cast<f16x8*>(&C_sm[r][c8]) = hv;
    }
    __syncthreads();
    f16x8 bfr = *reinterpret_cast<const f16x8*>(
        &WT[(long)(n0 + wave * 16 + ln) * CTXD + k0 + g * 8]);
#pragma unroll
    for (int mt = 0; mt < 5; ++mt) {
      f16x8 afr = *reinterpret_cast<const f16x8*>(&C_sm[mt * 16 + ln][g * 8]);
      acc[mt] = __builtin_amdgcn_mfma_f32_16x16x32_f16(afr, bfr, acc[mt], 0, 0, 0);
    }
  }

  const int n = n0 + wave * 16 + ln;
  const float bsv = bias[n];
  const int h = n / DH, dd = n % DH;
  if (kv == 0) {
#pragma unroll
    for (int mt = 0; mt < 5; ++mt)
#pragma unroll
      for (int r = 0; r < 4; ++r) {
        const int t = mt * 16 + g * 4 + r;
        k_ws[(((long)b * NH + h) * 80 + t) * DP + dd] = (half_t)(acc[mt][r] + bsv);
      }
  } else {
#pragma unroll
    for (int mt = 0; mt < 5; ++mt) {
      const int t0 = mt * 16 + g * 4;
      f16x4 v4;
#pragma unroll
      for (int r = 0; r < 4; ++r) v4[r] = (half_t)(acc[mt][r] + bsv);
      *reinterpret_cast<f16x4*>(&vT_ws[(((long)b * NH + h) * 80 + dd) * DP + t0]) = v4;
    }
  }
}

// ---------------- panel GEMM, 256x128, DOUBLE-BUFFER phase-split ------------
// Round-8 fix: round 7's __launch_bounds__(512,6) strangled the register
// allocator (VGPR 64->40, acc spilled to scratch: FETCH 54->347 MB, WRITE
// 164->984 MB, 346 us). The min-waves arg CAPS registers, it doesn't create
// occupancy. (512,4) restores the proven budget; 3 blocks/CU comes from the
// 48 KB LDS alone (floor(160/48)=3), registers permitting (~64V+64A/wave
// -> ~16 waves/SIMD capacity >> 6 needed).
// Schedule: 1-ahead double buffer; both A+B stages for (t+1) issue in
// phase 1; ONE vmcnt(0)+barrier at step end publishes buf[nxt].
template <int EPI>
__global__ __launch_bounds__(512, 4) void pgemm8_kernel(
    const half_t* __restrict__ A, const half_t* __restrict__ BT,
    const float* __restrict__ bias, void* __restrict__ outp) {
  __shared__ __align__(16) half_t A_sm[2][256 * 32];   // 32 KB
  __shared__ __align__(16) half_t B_sm[2][128 * 32];   // 16 KB
  const int tid = threadIdx.x;
  const int lane = tid & 63, wave = tid >> 6;   // wave 0..7
  const int g = lane >> 4, ln = lane & 15;
  const int wm = wave >> 1, wn = wave & 1;      // 4 x 2 wave grid

  int panel, nblk;
  xcd_panel_map(blockIdx.x, panel, nblk);
  const long m0 = (long)panel * 256;
  const int n0 = nblk * 128;

  // staging map (proven 0-conflict rounds 0-7)
  const int srow = tid >> 2;                                  // 0..127
  const int sk8 = ((tid & 3) ^ ((tid >> 3) & 3)) * 8;
  const half_t* ag0 = A + (m0 + srow) * CD + sk8;
  const half_t* ag1 = ag0 + 128 * CD;                         // rows 128..255
  const half_t* bg0 = BT + (long)(n0 + srow) * CD + sk8;

  // fragment-read slot (loop-invariant): g ^ ((ln>>1)&3)
  const int rs8 = (g ^ ((ln >> 1) & 3)) * 8;

  f32x4 acc[4][4];
#pragma unroll
  for (int i = 0; i < 4; ++i)
#pragma unroll
    for (int j = 0; j < 4; ++j) acc[i][j] = (f32x4){0.f, 0.f, 0.f, 0.f};

#define STAGE_AB(buf, kt)                                             \
  do {                                                                \
    GLOAD16(ag0 + (long)(kt) * 32, &A_sm[buf][wave * 512]);           \
    GLOAD16(ag1 + (long)(kt) * 32, &A_sm[buf][4096 + wave * 512]);    \
    GLOAD16(bg0 + (long)(kt) * 32, &B_sm[buf][wave * 512]);           \
  } while (0)

#define READ_A2(dst0, dst1, buf, mi0)                                 \
  do {                                                                \
    dst0 = *reinterpret_cast<const f16x8*>(                           \
        &A_sm[buf][(wm * 64 + (mi0) * 16 + ln) * 32 + rs8]);          \
    dst1 = *reinterpret_cast<const f16x8*>(                           \
        &A_sm[buf][(wm * 64 + ((mi0) + 1) * 16 + ln) * 32 + rs8]);    \
  } while (0)
#define READ_B4(bf, buf)                                              \
  do {                                                                \
    _Pragma("unroll")                                                 \
    for (int ni = 0; ni < 4; ++ni)                                    \
      bf[ni] = *reinterpret_cast<const f16x8*>(                       \
          &B_sm[buf][(wn * 64 + ni * 16 + ln) * 32 + rs8]);           \
  } while (0)

#define MFMA8(a0, a1, bf, mi0)                                        \
  do {                                                                \
    __builtin_amdgcn_s_setprio(1);                                    \
    _Pragma("unroll")                                                 \
    for (int ni = 0; ni < 4; ++ni)                                    \
      acc[mi0][ni] = __builtin_amdgcn_mfma_f32_16x16x32_f16(          \
          a0, bf[ni], acc[mi0][ni], 0, 0, 0);                         \
    _Pragma("unroll")                                                 \
    for (int ni = 0; ni < 4; ++ni)                                    \
      acc[(mi0) + 1][ni] = __builtin_amdgcn_mfma_f32_16x16x32_f16(    \
          a1, bf[ni], acc[(mi0) + 1][ni], 0, 0, 0);                   \
    __builtin_amdgcn_s_setprio(0);                                    \
  } while (0)

#define WAIT_LGKM_FENCE()                                             \
  do {                                                                \
    asm volatile("s_waitcnt lgkmcnt(0)" ::: "memory");                \
    __builtin_amdgcn_sched_barrier(0);                                \
  } while (0)

  // prologue: stage(0), drain, publish
  STAGE_AB(0, 0);
  asm volatile("s_waitcnt vmcnt(0)" ::: "memory");
  __builtin_amdgcn_s_barrier();

  const int nk = CD / 32;  // 20
  f16x8 a0, a1, a2, a3, bf[4];
  for (int t = 0; t < nk; ++t) {
    const int cur = t & 1, nxt = cur ^ 1;
    // ---- phase 1: reads + full stage(t+1) issue, 8 MFMA (mi 0,1) ----
    READ_A2(a0, a1, cur, 0);
    READ_B4(bf, cur);
    if (t + 1 < nk) STAGE_AB(nxt, t + 1);
    __builtin_amdgcn_s_barrier();
    WAIT_LGKM_FENCE();
    MFMA8(a0, a1, bf, 0);
    __builtin_amdgcn_s_barrier();
    // ---- phase 2: wave-private reads, 8 MFMA (mi 2,3), step-end drain ----
    READ_A2(a2, a3, cur, 2);
    WAIT_LGKM_FENCE();
    MFMA8(a2, a3, bf, 2);
    if (t + 1 < nk) {
      asm volatile("s_waitcnt vmcnt(0)" ::: "memory");   // stage(t+1) landed
      __builtin_amdgcn_s_barrier();                      // publish buf[nxt]
    }
  }

  if (EPI == 0) {
    half_t* O = (half_t*)outp;
#pragma unroll
    for (int ni = 0; ni < 4; ++ni) {
      const int n = n0 + wn * 64 + ni * 16 + ln;
      const float bvv = bias[n];
#pragma unroll
      for (int mi = 0; mi < 4; ++mi) {
        const long m = m0 + wm * 64 + mi * 16 + g * 4;
        f32x4 v = acc[mi][ni];
#pragma unroll
        for (int r = 0; r < 4; ++r)
          O[(m + r) * CD + n] = (half_t)(v[r] + bvv);
      }
    }
  } else {
    float* O = (float*)outp;
#pragma unroll
    for (int mi = 0; mi < 4; ++mi) {
      const long m = m0 + wm * 64 + mi * 16 + g * 4;
      const long bb = m >> 12;
      const int p = (int)(m & 4095);
#pragma unroll
      for (int ni = 0; ni < 4; ++ni) {
        const int n = n0 + wn * 64 + ni * 16 + ln;
        const float bvv = bias[n];
        f32x4 v = acc[mi][ni];
        float4 o4 = make_float4(v[0] + bvv, v[1] + bvv, v[2] + bvv, v[3] + bvv);
        *reinterpret_cast<float4*>(&O[((bb * CD + n) << 12) + p]) = o4;
      }
    }
  }
#undef STAGE_AB
#undef READ_A2
#undef READ_B4
#undef MFMA8
#undef WAIT_LGKM_FENCE
}

// ---------------- fused attention (128 px / block, 512 threads) -------------
__global__ __launch_bounds__(512) void attn_kernel(
    const half_t* __restrict__ q_ws, const half_t* __restrict__ k_ws,
    const half_t* __restrict__ vT_ws, half_t* __restrict__ attn_ws) {
  __shared__ half_t K_sm[80][DP];
  __shared__ half_t V_sm[80][DP];
  __shared__ half_t Q_sm[128][DP];  // becomes P after softmax (pads stay 0)
  const int p0 = blockIdx.x * 128;
  const int h  = blockIdx.y;
  const int b  = blockIdx.z;
  const int tid = threadIdx.x, wave = tid >> 6, lane = tid & 63;
  const int g = lane >> 4, ln = lane & 15;

  const half_t* kp = k_ws  + ((long)b * NH + h) * 80 * DP;
  const half_t* vp = vT_ws + ((long)b * NH + h) * 80 * DP;
  for (int i = tid; i < 960; i += 512) {   // 80*96/8 int4 chunks
    reinterpret_cast<int4*>(K_sm)[i] = reinterpret_cast<const int4*>(kp)[i];
    reinterpret_cast<int4*>(V_sm)[i] = reinterpret_cast<const int4*>(vp)[i];
  }
  for (int i = tid; i < 1536; i += 512) {  // 128 rows x 12 chunks
    const int r = i / 12, c8 = i % 12;
    int4 v = make_int4(0, 0, 0, 0);
    if (c8 < 10)
      v = *reinterpret_cast<const int4*>(
          q_ws + ((long)(b * HWD + p0 + r)) * CD + h * DH + c8 * 8);
    *reinterpret_cast<int4*>(&Q_sm[r][c8 * 8]) = v;
  }
  __syncthreads();

  // S^T = K(80x96) @ Q^T(96x16)
  f32x4 s[5];
#pragma unroll
  for (int i = 0; i < 5; ++i) s[i] = (f32x4){0.f, 0.f, 0.f, 0.f};
#pragma unroll
  for (int ks = 0; ks < 3; ++ks) {
    f16x8 bq = *reinterpret_cast<const f16x8*>(&Q_sm[wave * 16 + ln][ks * 32 + g * 8]);
#pragma unroll
    for (int mt = 0; mt < 5; ++mt) {
      f16x8 ak = *reinterpret_cast<const f16x8*>(&K_sm[mt * 16 + ln][ks * 32 + g * 8]);
      s[mt] = __builtin_amdgcn_mfma_f32_16x16x32_f16(ak, bq, s[mt], 0, 0, 0);
    }
  }

  // masked softmax over t (valid t<77)
  const float sc = 0.11180339887498949f;   // 80^-0.5
  float mx = -1e30f;
#pragma unroll
  for (int mt = 0; mt < 5; ++mt)
#pragma unroll
    for (int r = 0; r < 4; ++r) {
      const int t = mt * 16 + g * 4 + r;
      const float v = s[mt][r] * sc;
      s[mt][r] = v;
      if (t < TT) mx = fmaxf(mx, v);
    }
  mx = fmaxf(mx, __shfl_xor(mx, 16));
  mx = fmaxf(mx, __shfl_xor(mx, 32));
  float e[5][4];
  float sum = 0.f;
#pragma unroll
  for (int mt = 0; mt < 5; ++mt)
#pragma unroll
    for (int r = 0; r < 4; ++r) {
      const int t = mt * 16 + g * 4 + r;
      float ev = 0.f;
      if (t < TT) { ev = __expf(s[mt][r] - mx); sum += ev; }
      e[mt][r] = ev;
    }
  sum += __shfl_xor(sum, 16);
  sum += __shfl_xor(sum, 32);
  const float inv = 1.f / sum;
#pragma unroll
  for (int mt = 0; mt < 5; ++mt) {
    f16x4 pv;
#pragma unroll
    for (int r = 0; r < 4; ++r) pv[r] = (half_t)(e[mt][r] * inv);
    *reinterpret_cast<f16x4*>(&Q_sm[wave * 16 + ln][mt * 16 + g * 4]) = pv;
  }

  // O^T = V^T(80x96) @ P(96x16)
  f32x4 o[5];
#pragma unroll
  for (int i = 0; i < 5; ++i) o[i] = (f32x4){0.f, 0.f, 0.f, 0.f};
#pragma unroll
  for (int ks = 0; ks < 3; ++ks) {
    f16x8 bp = *reinterpret_cast<const f16x8*>(&Q_sm[wave * 16 + ln][ks * 32 + g * 8]);
#pragma unroll
    for (int mt = 0; mt < 5; ++mt) {
      f16x8 av = *reinterpret_cast<const f16x8*>(&V_sm[mt * 16 + ln][ks * 32 + g * 8]);
      o[mt] = __builtin_amdgcn_mfma_f32_16x16x32_f16(av, bp, o[mt], 0, 0, 0);
    }
  }

  half_t* op = attn_ws + ((long)(b * HWD + p0 + wave * 16 + ln)) * CD + h * DH;
#pragma unroll
  for (int mt = 0; mt < 5; ++mt) {
    f16x4 v4;
#pragma unroll
    for (int r = 0; r < 4; ++r) v4[r] = (half_t)o[mt][r];
    *reinterpret_cast<f16x4*>(&op[mt * 16 + g * 4]) = v4;
  }
}

// ---------------- launch ----------------
extern "C" void kernel_launch(void* const* d_in, const int* in_sizes, int n_in,
                              void* d_out, int out_size, void* d_ws, size_t ws_size,
                              hipStream_t stream) {
  const float* x   = (const float*)d_in[0];
  const float* ctx = (const float*)d_in[1];
  const float* Wq  = (const float*)d_in[2];
  const float* bq  = (const float*)d_in[3];
  const float* Wk  = (const float*)d_in[4];
  const float* bk  = (const float*)d_in[5];
  const float* Wv  = (const float*)d_in[6];
  const float* bv  = (const float*)d_in[7];
  const float* Wo  = (const float*)d_in[8];
  const float* bo  = (const float*)d_in[9];
  float* out = (float*)d_out;

  char* ws = (char*)d_ws;
  size_t off = 0;
  auto alloc = [&](size_t bytes) {
    void* p = ws + off;
    off += (bytes + 255) & ~(size_t)255;
    return p;
  };
  half_t* WqT  = (half_t*)alloc((size_t)CD * CD * 2);
  half_t* WkT  = (half_t*)alloc((size_t)CD * CTXD * 2);
  half_t* WvT  = (half_t*)alloc((size_t)CD * CTXD * 2);
  half_t* WoT  = (half_t*)alloc((size_t)CD * CD * 2);
  half_t* kws  = (half_t*)alloc((size_t)NB * NH * 80 * DP * 2);
  half_t* vTws = (half_t*)alloc((size_t)NB * NH * 80 * DP * 2);
  half_t* xt   = (half_t*)alloc((size_t)NB * HWD * CD * 2);
  half_t* q    = (half_t*)alloc((size_t)NB * HWD * CD * 2);
  half_t* attn = xt;   // xt dead after pgemm8<0>; alias

  // weight transposes (f32 -> f16)
  wtrans_kernel<<<dim3(CD / 64, CTXD / 64, 4), 256, 0, stream>>>(
      Wq, Wk, Wv, Wo, WqT, WkT, WvT, WoT);

  // K/V projection (+ pad zeroing)
  kv_kernel<<<dim3(CD / 64, NB, 2), 256, 0, stream>>>(ctx, WkT, WvT, bk, bv, kws, vTws);

  // x transpose + convert
  xpose_kernel<<<dim3(HWD / 64, CD / 64, NB), 256, 0, stream>>>(x, xt);

  // Q projection (256x128 tiles, double-buffer phase-split, 3 blk/CU by LDS)
  pgemm8_kernel<0><<<(CD / 128) * ((NB * HWD) / 256), 512, 0, stream>>>(
      xt, WqT, bq, q);

  // fused attention (128 px / block)
  attn_kernel<<<dim3(HWD / 128, NH, NB), 512, 0, stream>>>(q, kws, vTws, attn);

  // O projection (256x128 tiles, double-buffer phase-split, 3 blk/CU by LDS)
  pgemm8_kernel<1><<<(CD / 128) * ((NB * HWD) / 256), 512, 0, stream>>>(
      attn, WoT, bo, out);
}

// Round 9
// 296.674 us; speedup vs baseline: 2.7133x; 1.0431x over previous
//
#include <hip/hip_runtime.h>
#include <hip/hip_fp16.h>

typedef _Float16 half_t;
typedef _Float16 f16x8 __attribute__((ext_vector_type(8)));
typedef _Float16 f16x4 __attribute__((ext_vector_type(4)));
typedef float f32x4 __attribute__((ext_vector_type(4)));

// problem constants
#define NB   16
#define CD   640
#define HWD  4096
#define TT   77
#define CTXD 768
#define NH   8
#define DH   80
#define DP   96   // padded d / padded T for the attention kernel

#define GLOAD16(gp, lp)                                                        \
  __builtin_amdgcn_global_load_lds(                                            \
      (const __attribute__((address_space(1))) void*)(gp),                     \
      (__attribute__((address_space(3))) void*)(lp), 16, 0, 0)

// XCD-locality swizzle: 5 n-blocks of one 256-row m-panel -> same XCD.
// grid = 1280 = 8 XCD * 160 slots; 256 panels (%8==0) -> bijective.
__device__ inline void xcd_panel_map(int j, int& panel, int& nblk) {
  const int xcd = j & 7, slot = j >> 3;
  panel = (slot / 5) * 8 + xcd;
  nblk = slot % 5;
}

// ---------------- x transpose + f32->f16 convert ----------------
// x (B, 640, 4096) f32 -> xt (B, 4096, 640) f16
__global__ __launch_bounds__(256) void xpose_kernel(
    const float* __restrict__ x, half_t* __restrict__ xt) {
  __shared__ half_t tile[64][72];
  const float* s = x + (long)blockIdx.z * CD * HWD;
  half_t* d = xt + (long)blockIdx.z * HWD * CD;
  const int r0 = blockIdx.y * 64;   // channel
  const int c0 = blockIdx.x * 64;   // pixel
  const int t = threadIdx.x;
  const int rr = t >> 4, cc = (t & 15) * 4;
#pragma unroll
  for (int j = 0; j < 4; ++j) {
    const int r = rr + j * 16;
    float4 v = *reinterpret_cast<const float4*>(&s[(long)(r0 + r) * HWD + c0 + cc]);
    tile[cc + 0][r] = (half_t)v.x;
    tile[cc + 1][r] = (half_t)v.y;
    tile[cc + 2][r] = (half_t)v.z;
    tile[cc + 3][r] = (half_t)v.w;
  }
  __syncthreads();
  const int cr = t >> 2, rc = (t & 3) * 16;
  half_t* dp = &d[(long)(c0 + cr) * CD + r0 + rc];
  *reinterpret_cast<int4*>(dp)     = *reinterpret_cast<const int4*>(&tile[cr][rc]);
  *reinterpret_cast<int4*>(dp + 8) = *reinterpret_cast<const int4*>(&tile[cr][rc + 8]);
}

// ---------------- merged weight transpose + f32->f16 convert ----------------
__global__ __launch_bounds__(256) void wtrans_kernel(
    const float* __restrict__ Wq, const float* __restrict__ Wk,
    const float* __restrict__ Wv, const float* __restrict__ Wo,
    half_t* __restrict__ WqT, half_t* __restrict__ WkT,
    half_t* __restrict__ WvT, half_t* __restrict__ WoT) {
  __shared__ half_t tile[64][72];
  const int z = blockIdx.z;
  const float* src = (z == 0) ? Wq : (z == 1) ? Wk : (z == 2) ? Wv : Wo;
  half_t* dst      = (z == 0) ? WqT : (z == 1) ? WkT : (z == 2) ? WvT : WoT;
  const int R = (z == 1 || z == 2) ? CTXD : CD;
  const int r0 = blockIdx.y * 64, c0 = blockIdx.x * 64;
  if (r0 >= R) return;
  const int t = threadIdx.x;
  const int rr = t >> 4, cc = (t & 15) * 4;
#pragma unroll
  for (int j = 0; j < 4; ++j) {
    const int r = rr + j * 16;
    float4 v = *reinterpret_cast<const float4*>(&src[(long)(r0 + r) * CD + c0 + cc]);
    tile[cc + 0][r] = (half_t)v.x;
    tile[cc + 1][r] = (half_t)v.y;
    tile[cc + 2][r] = (half_t)v.z;
    tile[cc + 3][r] = (half_t)v.w;
  }
  __syncthreads();
  const int cr = t >> 2, rc = (t & 3) * 16;
  half_t* dp = &dst[(long)(c0 + cr) * R + r0 + rc];
  *reinterpret_cast<int4*>(dp)     = *reinterpret_cast<const int4*>(&tile[cr][rc]);
  *reinterpret_cast<int4*>(dp + 8) = *reinterpret_cast<const int4*>(&tile[cr][rc + 8]);
}

// ---------------- K/V projection ----------------
// ctx (B,77,768) f32 @ WT(640,768)^T + bias ->
//   kv==0: k_ws  (B, 8, 80, 96)  [t][dd]
//   kv==1: vT_ws (B, 8, 80, 96)  [dd][t]
// Pad columns [80,96) zeroed here (block x==0 of each (b,kv)).
__global__ __launch_bounds__(256) void kv_kernel(
    const float* __restrict__ ctx,
    const half_t* __restrict__ WkT, const half_t* __restrict__ WvT,
    const float* __restrict__ bk, const float* __restrict__ bv,
    half_t* __restrict__ k_ws, half_t* __restrict__ vT_ws) {
  __shared__ half_t C_sm[80][32];
  const int n0 = blockIdx.x * 64;
  const int b  = blockIdx.y;
  const int kv = blockIdx.z;
  const half_t* WT  = kv ? WvT : WkT;
  const float* bias = kv ? bv : bk;
  const int tid = threadIdx.x;
  const int wave = tid >> 6, lane = tid & 63, g = lane >> 4, ln = lane & 15;

  if (blockIdx.x == 0) {
    half_t* dst = kv ? vT_ws : k_ws;
    for (int i = tid; i < 1280; i += 256) {   // 8h * 80rows * 2 chunks
      const int hh = i / 160, rr = i % 160;
      half_t* p = dst + (((long)b * NH + hh) * 80 + (rr >> 1)) * DP + 80 + (rr & 1) * 8;
      *reinterpret_cast<int4*>(p) = make_int4(0, 0, 0, 0);
    }
  }

  f32x4 acc[5];
#pragma unroll
  for (int i = 0; i < 5; ++i) acc[i] = (f32x4){0.f, 0.f, 0.f, 0.f};

  for (int k0 = 0; k0 < CTXD; k0 += 32) {
    if (k0) __syncthreads();
    for (int i = tid; i < 320; i += 256) {
      const int r = i >> 2, c8 = (i & 3) * 8;
      f16x8 hv = {0, 0, 0, 0, 0, 0, 0, 0};
      if (r < TT) {
        const float* cp = ctx + ((long)b * TT + r) * CTXD + k0 + c8;
        float4 c0v = *reinterpret_cast<const float4*>(cp);
        float4 c1v = *reinterpret_cast<const float4*>(cp + 4);
        hv[0] = (half_t)c0v.x; hv[1] = (half_t)c0v.y;
        hv[2] = (half_t)c0v.z; hv[3] = (half_t)c0v.w;
        hv[4] = (half_t)c1v.x; hv[5] = (half_t)c1v.y;
        hv[6] = (half_t)c1v.z; hv[7] = (half_t)c1v.w;
      }
      *reinterpret_cast<f16x8*>(&C_sm[r][c8]) = hv;
    }
    __syncthreads();
    f16x8 bfr = *reinterpret_cast<const f16x8*>(
        &WT[(long)(n0 + wave * 16 + ln) * CTXD + k0 + g * 8]);
#pragma unroll
    for (int mt = 0; mt < 5; ++mt) {
      f16x8 afr = *reinterpret_cast<const f16x8*>(&C_sm[mt * 16 + ln][g * 8]);
      acc[mt] = __builtin_amdgcn_mfma_f32_16x16x32_f16(afr, bfr, acc[mt], 0, 0, 0);
    }
  }

  const int n = n0 + wave * 16 + ln;
  const float bsv = bias[n];
  const int h = n / DH, dd = n % DH;
  if (kv == 0) {
#pragma unroll
    for (int mt = 0; mt < 5; ++mt)
#pragma unroll
      for (int r = 0; r < 4; ++r) {
        const int t = mt * 16 + g * 4 + r;
        k_ws[(((long)b * NH + h) * 80 + t) * DP + dd] = (half_t)(acc[mt][r] + bsv);
      }
  } else {
#pragma unroll
    for (int mt = 0; mt < 5; ++mt) {
      const int t0 = mt * 16 + g * 4;
      f16x4 v4;
#pragma unroll
      for (int r = 0; r < 4; ++r) v4[r] = (half_t)(acc[mt][r] + bsv);
      *reinterpret_cast<f16x4*>(&vT_ws[(((long)b * NH + h) * 80 + dd) * DP + t0]) = v4;
    }
  }
}

// ---------------- panel GEMM, 256x128 tile, PHASE-SPLIT schedule ------------
// Round-6's best-verified kernel, restored verbatim (96 us, MfmaUtil 23,
// conflicts 0; rounds 7-8 showed occupancy is register-bound -> double
// buffer gains nothing). Triple buffer, 2 phases of 8 MFMA per BK=32 step,
// counted vmcnt(3) once per step, setprio around MFMA.
template <int EPI>
__global__ __launch_bounds__(512, 4) void pgemm8_kernel(
    const half_t* __restrict__ A, const half_t* __restrict__ BT,
    const float* __restrict__ bias, void* __restrict__ outp) {
  __shared__ __align__(16) half_t A_sm[3][256 * 32];   // 48 KB
  __shared__ __align__(16) half_t B_sm[3][128 * 32];   // 24 KB
  const int tid = threadIdx.x;
  const int lane = tid & 63, wave = tid >> 6;   // wave 0..7
  const int g = lane >> 4, ln = lane & 15;
  const int wm = wave >> 1, wn = wave & 1;      // 4 x 2 wave grid

  int panel, nblk;
  xcd_panel_map(blockIdx.x, panel, nblk);
  const long m0 = (long)panel * 256;
  const int n0 = nblk * 128;

  // staging: lane l -> row wave*16+(l>>2), phys slot l&3 holds source
  // k-chunk (l&3)^((l>>3)&3)  [proven 0-conflict, rounds 0-8]
  const int srow = tid >> 2;                                  // 0..127
  const int sk8 = ((tid & 3) ^ ((tid >> 3) & 3)) * 8;
  const half_t* ag0 = A + (m0 + srow) * CD + sk8;
  const half_t* ag1 = ag0 + 128 * CD;                         // rows 128..255
  const half_t* bg0 = BT + (long)(n0 + srow) * CD + sk8;

  // fragment-read slot (loop-invariant): g ^ ((ln>>1)&3)
  const int rs8 = (g ^ ((ln >> 1) & 3)) * 8;

  f32x4 acc[4][4];
#pragma unroll
  for (int i = 0; i < 4; ++i)
#pragma unroll
    for (int j = 0; j < 4; ++j) acc[i][j] = (f32x4){0.f, 0.f, 0.f, 0.f};

#define STAGE_A(buf, kt)                                              \
  do {                                                                \
    GLOAD16(ag0 + (long)(kt) * 32, &A_sm[buf][wave * 512]);           \
    GLOAD16(ag1 + (long)(kt) * 32, &A_sm[buf][4096 + wave * 512]);    \
  } while (0)
#define STAGE_B(buf, kt)                                              \
  GLOAD16(bg0 + (long)(kt) * 32, &B_sm[buf][wave * 512])

#define READ_A2(dst0, dst1, buf, mi0)                                 \
  do {                                                                \
    dst0 = *reinterpret_cast<const f16x8*>(                           \
        &A_sm[buf][(wm * 64 + (mi0) * 16 + ln) * 32 + rs8]);          \
    dst1 = *reinterpret_cast<const f16x8*>(                           \
        &A_sm[buf][(wm * 64 + ((mi0) + 1) * 16 + ln) * 32 + rs8]);    \
  } while (0)
#define READ_B4(bf, buf)                                              \
  do {                                                                \
    _Pragma("unroll")                                                 \
    for (int ni = 0; ni < 4; ++ni)                                    \
      bf[ni] = *reinterpret_cast<const f16x8*>(                       \
          &B_sm[buf][(wn * 64 + ni * 16 + ln) * 32 + rs8]);           \
  } while (0)

#define MFMA8(a0, a1, bf, mi0)                                        \
  do {                                                                \
    __builtin_amdgcn_s_setprio(1);                                    \
    _Pragma("unroll")                                                 \
    for (int ni = 0; ni < 4; ++ni)                                    \
      acc[mi0][ni] = __builtin_amdgcn_mfma_f32_16x16x32_f16(          \
          a0, bf[ni], acc[mi0][ni], 0, 0, 0);                         \
    _Pragma("unroll")                                                 \
    for (int ni = 0; ni < 4; ++ni)                                    \
      acc[(mi0) + 1][ni] = __builtin_amdgcn_mfma_f32_16x16x32_f16(    \
          a1, bf[ni], acc[(mi0) + 1][ni], 0, 0, 0);                   \
    __builtin_amdgcn_s_setprio(0);                                    \
  } while (0)

#define WAIT_LGKM_FENCE()                                             \
  do {                                                                \
    asm volatile("s_waitcnt lgkmcnt(0)" ::: "memory");                \
    __builtin_amdgcn_sched_barrier(0);                                \
  } while (0)

  // prologue: stage(0), stage(1); drain stage(0) (vmcnt: 6 out -> keep 3)
  STAGE_A(0, 0); STAGE_B(0, 0);
  STAGE_A(1, 1); STAGE_B(1, 1);
  asm volatile("s_waitcnt vmcnt(3)" ::: "memory");
  __builtin_amdgcn_s_barrier();

  const int nk = CD / 32;  // 20
  f16x8 a0, a1, a2, a3, bf[4];
  for (int t = 0; t < nk - 2; ++t) {
    const int cur = t % 3, nxt = (t + 2) % 3;
    // ---- phase 1: reads + A-stage issue, then 8 MFMA (mi 0,1) ----
    READ_A2(a0, a1, cur, 0);
    READ_B4(bf, cur);
    STAGE_A(nxt, t + 2);
    __builtin_amdgcn_s_barrier();
    WAIT_LGKM_FENCE();
    MFMA8(a0, a1, bf, 0);
    __builtin_amdgcn_s_barrier();
    // ---- phase 2: reads + B-stage issue + boundary vmcnt, 8 MFMA (mi 2,3) --
    READ_A2(a2, a3, cur, 2);
    STAGE_B(nxt, t + 2);
    asm volatile("s_waitcnt vmcnt(3)" ::: "memory");   // stage(t+1) arrived
    __builtin_amdgcn_s_barrier();
    WAIT_LGKM_FENCE();
    MFMA8(a2, a3, bf, 2);
    __builtin_amdgcn_s_barrier();
  }
  // t = nk-2: no issue; drain stage(nk-1)
  {
    const int cur = (nk - 2) % 3;
    READ_A2(a0, a1, cur, 0);
    READ_B4(bf, cur);
    __builtin_amdgcn_s_barrier();
    WAIT_LGKM_FENCE();
    MFMA8(a0, a1, bf, 0);
    __builtin_amdgcn_s_barrier();
    READ_A2(a2, a3, cur, 2);
    asm volatile("s_waitcnt vmcnt(0)" ::: "memory");
    __builtin_amdgcn_s_barrier();
    WAIT_LGKM_FENCE();
    MFMA8(a2, a3, bf, 2);
    __builtin_amdgcn_s_barrier();
  }
  // t = nk-1: compute only
  {
    const int cur = (nk - 1) % 3;
    READ_A2(a0, a1, cur, 0);
    READ_B4(bf, cur);
    WAIT_LGKM_FENCE();
    MFMA8(a0, a1, bf, 0);
    READ_A2(a2, a3, cur, 2);
    WAIT_LGKM_FENCE();
    MFMA8(a2, a3, bf, 2);
  }

  if (EPI == 0) {
    half_t* O = (half_t*)outp;
#pragma unroll
    for (int ni = 0; ni < 4; ++ni) {
      const int n = n0 + wn * 64 + ni * 16 + ln;
      const float bvv = bias[n];
#pragma unroll
      for (int mi = 0; mi < 4; ++mi) {
        const long m = m0 + wm * 64 + mi * 16 + g * 4;
        f32x4 v = acc[mi][ni];
#pragma unroll
        for (int r = 0; r < 4; ++r)
          O[(m + r) * CD + n] = (half_t)(v[r] + bvv);
      }
    }
  } else {
    float* O = (float*)outp;
#pragma unroll
    for (int mi = 0; mi < 4; ++mi) {
      const long m = m0 + wm * 64 + mi * 16 + g * 4;
      const long bb = m >> 12;
      const int p = (int)(m & 4095);
#pragma unroll
      for (int ni = 0; ni < 4; ++ni) {
        const int n = n0 + wn * 64 + ni * 16 + ln;
        const float bvv = bias[n];
        f32x4 v = acc[mi][ni];
        float4 o4 = make_float4(v[0] + bvv, v[1] + bvv, v[2] + bvv, v[3] + bvv);
        *reinterpret_cast<float4*>(&O[((bb * CD + n) << 12) + p]) = o4;
      }
    }
  }
#undef STAGE_A
#undef STAGE_B
#undef READ_A2
#undef READ_B4
#undef MFMA8
#undef WAIT_LGKM_FENCE
}

// ---------------- fused attention (256 px / block, pipelined) ---------------
// Round-9 rework: 256 px per block as TWO 128-px tiles sharing one K/V load.
// ALL global loads (K/V 4 int4, Q-tile0 3 int4, Q-tile1 3 int4) issue
// up-front into registers -> tile-1's HBM latency hides under K/V staging
// and tile-0 compute (T14).  Q staging is WAVE-PRIVATE (wave w stages only
// its own 16 rows), so Q/P LDS traffic needs no barriers: per-wave DS ops
// complete in order, and tile-1's Q writes follow tile-0's PV reads in
// program order. Single __syncthreads (K/V visibility). Tile-1 Q reads are
// fenced by lgkmcnt(0)+sched_barrier (rule #18).
__global__ __launch_bounds__(512) void attn_kernel(
    const half_t* __restrict__ q_ws, const half_t* __restrict__ k_ws,
    const half_t* __restrict__ vT_ws, half_t* __restrict__ attn_ws) {
  __shared__ half_t K_sm[80][DP];
  __shared__ half_t V_sm[80][DP];
  __shared__ half_t Q_sm[128][DP];  // per-wave 16-row slices; reused per tile
  const int p0 = blockIdx.x * 256;
  const int h  = blockIdx.y;
  const int b  = blockIdx.z;
  const int tid = threadIdx.x, wave = tid >> 6, lane = tid & 63;
  const int g = lane >> 4, ln = lane & 15;

  // ---- issue ALL global loads up-front ----
  const int4* kp4 = reinterpret_cast<const int4*>(k_ws  + ((long)b * NH + h) * 80 * DP);
  const int4* vp4 = reinterpret_cast<const int4*>(vT_ws + ((long)b * NH + h) * 80 * DP);
  int4 kr0, kr1, vr0, vr1;
  kr0 = kp4[tid];
  vr0 = vp4[tid];
  const int i2 = tid + 512;
  if (i2 < 960) { kr1 = kp4[i2]; vr1 = vp4[i2]; }

  // Q chunks, wave-private: wave stages its own rows [wave*16, wave*16+16)
  // chunk c = lane + j*64 in [0,192): row = wave*16 + c/12, c8 = c%12
  int qr_[3], qc_[3];
  int4 q0r[3], q1r[3];
#pragma unroll
  for (int j = 0; j < 3; ++j) {
    const int c = lane + j * 64;
    qr_[j] = wave * 16 + c / 12;
    qc_[j] = c % 12;
    q0r[j] = make_int4(0, 0, 0, 0);
    q1r[j] = make_int4(0, 0, 0, 0);
    if (qc_[j] < 10)
      q0r[j] = *reinterpret_cast<const int4*>(
          q_ws + ((long)(b * HWD + p0 + qr_[j])) * CD + h * DH + qc_[j] * 8);
  }
#pragma unroll
  for (int j = 0; j < 3; ++j) {
    if (qc_[j] < 10)
      q1r[j] = *reinterpret_cast<const int4*>(
          q_ws + ((long)(b * HWD + p0 + 128 + qr_[j])) * CD + h * DH + qc_[j] * 8);
  }

  // ---- LDS writes: K/V (shared) + Q tile0 (wave-private) ----
  reinterpret_cast<int4*>(K_sm)[tid] = kr0;
  reinterpret_cast<int4*>(V_sm)[tid] = vr0;
  if (i2 < 960) {
    reinterpret_cast<int4*>(K_sm)[i2] = kr1;
    reinterpret_cast<int4*>(V_sm)[i2] = vr1;
  }
#pragma unroll
  for (int j = 0; j < 3; ++j)
    *reinterpret_cast<int4*>(&Q_sm[qr_[j]][qc_[j] * 8]) = q0r[j];
  __syncthreads();   // K/V visible to all waves (also drains Q0 writes)

  const float sc = 0.11180339887498949f;   // 80^-0.5

#define TILE_COMPUTE(toff)                                                     \
  do {                                                                         \
    f32x4 s[5];                                                                \
    _Pragma("unroll") for (int i = 0; i < 5; ++i)                              \
        s[i] = (f32x4){0.f, 0.f, 0.f, 0.f};                                    \
    _Pragma("unroll") for (int ks = 0; ks < 3; ++ks) {                         \
      f16x8 bq = *reinterpret_cast<const f16x8*>(                              \
          &Q_sm[wave * 16 + ln][ks * 32 + g * 8]);                             \
      _Pragma("unroll") for (int mt = 0; mt < 5; ++mt) {                       \
        f16x8 ak = *reinterpret_cast<const f16x8*>(                            \
            &K_sm[mt * 16 + ln][ks * 32 + g * 8]);                             \
        s[mt] = __builtin_amdgcn_mfma_f32_16x16x32_f16(ak, bq, s[mt], 0, 0, 0);\
      }                                                                        \
    }                                                                          \
    float mx = -1e30f;                                                         \
    _Pragma("unroll") for (int mt = 0; mt < 5; ++mt)                           \
      _Pragma("unroll") for (int r = 0; r < 4; ++r) {                          \
        const int t = mt * 16 + g * 4 + r;                                     \
        const float v = s[mt][r] * sc;                                         \
        s[mt][r] = v;                                                          \
        if (t < TT) mx = fmaxf(mx, v);                                         \
      }                                                                        \
    mx = fmaxf(mx, __shfl_xor(mx, 16));                                        \
    mx = fmaxf(mx, __shfl_xor(mx, 32));                                        \
    float e[5][4];                                                             \
    float sum = 0.f;                                                           \
    _Pragma("unroll") for (int mt = 0; mt < 5; ++mt)                           \
      _Pragma("unroll") for (int r = 0; r < 4; ++r) {                          \
        const int t = mt * 16 + g * 4 + r;                                     \
        float ev = 0.f;                                                        \
        if (t < TT) { ev = __expf(s[mt][r] - mx); sum += ev; }                 \
        e[mt][r] = ev;                                                         \
      }                                                                        \
    sum += __shfl_xor(sum, 16);                                                \
    sum += __shfl_xor(sum, 32);                                                \
    const float inv = 1.f / sum;                                               \
    _Pragma("unroll") for (int mt = 0; mt < 5; ++mt) {                         \
      f16x4 pv;                                                                \
      _Pragma("unroll") for (int r = 0; r < 4; ++r)                            \
        pv[r] = (half_t)(e[mt][r] * inv);                                      \
      *reinterpret_cast<f16x4*>(&Q_sm[wave * 16 + ln][mt * 16 + g * 4]) = pv;  \
    }                                                                          \
    f32x4 o[5];                                                                \
    _Pragma("unroll") for (int i = 0; i < 5; ++i)                              \
        o[i] = (f32x4){0.f, 0.f, 0.f, 0.f};                                    \
    _Pragma("unroll") for (int ks = 0; ks < 3; ++ks) {                         \
      f16x8 bp = *reinterpret_cast<const f16x8*>(                              \
          &Q_sm[wave * 16 + ln][ks * 32 + g * 8]);                             \
      _Pragma("unroll") for (int mt = 0; mt < 5; ++mt) {                       \
        f16x8 av = *reinterpret_cast<const f16x8*>(                            \
            &V_sm[mt * 16 + ln][ks * 32 + g * 8]);                             \
        o[mt] = __builtin_amdgcn_mfma_f32_16x16x32_f16(av, bp, o[mt], 0, 0, 0);\
      }                                                                        \
    }                                                                          \
    half_t* op = attn_ws +                                                     \
        ((long)(b * HWD + p0 + (toff) + wave * 16 + ln)) * CD + h * DH;        \
    _Pragma("unroll") for (int mt = 0; mt < 5; ++mt) {                         \
      f16x4 v4;                                                                \
      _Pragma("unroll") for (int r = 0; r < 4; ++r)                            \
        v4[r] = (half_t)o[mt][r];                                              \
      *reinterpret_cast<f16x4*>(&op[mt * 16 + g * 4]) = v4;                    \
    }                                                                          \
  } while (0)

  // ---- tile 0 ----
  TILE_COMPUTE(0);

  // ---- stage Q tile1 (wave-private; follows this wave's PV reads in the
  // in-order DS pipe, so no barrier) ----
#pragma unroll
  for (int j = 0; j < 3; ++j)
    *reinterpret_cast<int4*>(&Q_sm[qr_[j]][qc_[j] * 8]) = q1r[j];
  asm volatile("s_waitcnt lgkmcnt(0)" ::: "memory");
  __builtin_amdgcn_sched_barrier(0);

  // ---- tile 1 ----
  TILE_COMPUTE(128);
#undef TILE_COMPUTE
}

// ---------------- launch ----------------
extern "C" void kernel_launch(void* const* d_in, const int* in_sizes, int n_in,
                              void* d_out, int out_size, void* d_ws, size_t ws_size,
                              hipStream_t stream) {
  const float* x   = (const float*)d_in[0];
  const float* ctx = (const float*)d_in[1];
  const float* Wq  = (const float*)d_in[2];
  const float* bq  = (const float*)d_in[3];
  const float* Wk  = (const float*)d_in[4];
  const float* bk  = (const float*)d_in[5];
  const float* Wv  = (const float*)d_in[6];
  const float* bv  = (const float*)d_in[7];
  const float* Wo  = (const float*)d_in[8];
  const float* bo  = (const float*)d_in[9];
  float* out = (float*)d_out;

  char* ws = (char*)d_ws;
  size_t off = 0;
  auto alloc = [&](size_t bytes) {
    void* p = ws + off;
    off += (bytes + 255) & ~(size_t)255;
    return p;
  };
  half_t* WqT  = (half_t*)alloc((size_t)CD * CD * 2);
  half_t* WkT  = (half_t*)alloc((size_t)CD * CTXD * 2);
  half_t* WvT  = (half_t*)alloc((size_t)CD * CTXD * 2);
  half_t* WoT  = (half_t*)alloc((size_t)CD * CD * 2);
  half_t* kws  = (half_t*)alloc((size_t)NB * NH * 80 * DP * 2);
  half_t* vTws = (half_t*)alloc((size_t)NB * NH * 80 * DP * 2);
  half_t* xt   = (half_t*)alloc((size_t)NB * HWD * CD * 2);
  half_t* q    = (half_t*)alloc((size_t)NB * HWD * CD * 2);
  half_t* attn = xt;   // xt dead after pgemm8<0>; alias

  // weight transposes (f32 -> f16)
  wtrans_kernel<<<dim3(CD / 64, CTXD / 64, 4), 256, 0, stream>>>(
      Wq, Wk, Wv, Wo, WqT, WkT, WvT, WoT);

  // K/V projection (+ pad zeroing)
  kv_kernel<<<dim3(CD / 64, NB, 2), 256, 0, stream>>>(ctx, WkT, WvT, bk, bv, kws, vTws);

  // x transpose + convert
  xpose_kernel<<<dim3(HWD / 64, CD / 64, NB), 256, 0, stream>>>(x, xt);

  // Q projection (256x128 tiles, phase-split schedule)
  pgemm8_kernel<0><<<(CD / 128) * ((NB * HWD) / 256), 512, 0, stream>>>(
      xt, WqT, bq, q);

  // fused attention (256 px / block, pipelined 2 tiles)
  attn_kernel<<<dim3(HWD / 256, NH, NB), 512, 0, stream>>>(q, kws, vTws, attn);

  // O projection (256x128 tiles, phase-split schedule)
  pgemm8_kernel<1><<<(CD / 128) * ((NB * HWD) / 256), 512, 0, stream>>>(
      attn, WoT, bo, out);
}

// Round 10
// 294.207 us; speedup vs baseline: 2.7360x; 1.0084x over previous
//
#include <hip/hip_runtime.h>
#include <hip/hip_fp16.h>

typedef _Float16 half_t;
typedef _Float16 f16x8 __attribute__((ext_vector_type(8)));
typedef _Float16 f16x4 __attribute__((ext_vector_type(4)));
typedef float f32x4 __attribute__((ext_vector_type(4)));

// problem constants
#define NB   16
#define CD   640
#define HWD  4096
#define TT   77
#define CTXD 768
#define NH   8
#define DH   80
#define DP   96   // padded d / padded T for the attention kernel

#define GLOAD16(gp, lp)                                                        \
  __builtin_amdgcn_global_load_lds(                                            \
      (const __attribute__((address_space(1))) void*)(gp),                     \
      (__attribute__((address_space(3))) void*)(lp), 16, 0, 0)

// XCD-locality swizzle: 5 n-blocks of one 256-row m-panel -> same XCD.
// grid = 1280 = 8 XCD * 160 slots; 256 panels (%8==0) -> bijective.
__device__ inline void xcd_panel_map(int j, int& panel, int& nblk) {
  const int xcd = j & 7, slot = j >> 3;
  panel = (slot / 5) * 8 + xcd;
  nblk = slot % 5;
}

// ---------------- x transpose + f32->f16 convert ----------------
// x (B, 640, 4096) f32 -> xt (B, 4096, 640) f16
__global__ __launch_bounds__(256) void xpose_kernel(
    const float* __restrict__ x, half_t* __restrict__ xt) {
  __shared__ half_t tile[64][72];
  const float* s = x + (long)blockIdx.z * CD * HWD;
  half_t* d = xt + (long)blockIdx.z * HWD * CD;
  const int r0 = blockIdx.y * 64;   // channel
  const int c0 = blockIdx.x * 64;   // pixel
  const int t = threadIdx.x;
  const int rr = t >> 4, cc = (t & 15) * 4;
#pragma unroll
  for (int j = 0; j < 4; ++j) {
    const int r = rr + j * 16;
    float4 v = *reinterpret_cast<const float4*>(&s[(long)(r0 + r) * HWD + c0 + cc]);
    tile[cc + 0][r] = (half_t)v.x;
    tile[cc + 1][r] = (half_t)v.y;
    tile[cc + 2][r] = (half_t)v.z;
    tile[cc + 3][r] = (half_t)v.w;
  }
  __syncthreads();
  const int cr = t >> 2, rc = (t & 3) * 16;
  half_t* dp = &d[(long)(c0 + cr) * CD + r0 + rc];
  *reinterpret_cast<int4*>(dp)     = *reinterpret_cast<const int4*>(&tile[cr][rc]);
  *reinterpret_cast<int4*>(dp + 8) = *reinterpret_cast<const int4*>(&tile[cr][rc + 8]);
}

// ---------------- merged weight transpose + f32->f16 convert ----------------
__global__ __launch_bounds__(256) void wtrans_kernel(
    const float* __restrict__ Wq, const float* __restrict__ Wk,
    const float* __restrict__ Wv, const float* __restrict__ Wo,
    half_t* __restrict__ WqT, half_t* __restrict__ WkT,
    half_t* __restrict__ WvT, half_t* __restrict__ WoT) {
  __shared__ half_t tile[64][72];
  const int z = blockIdx.z;
  const float* src = (z == 0) ? Wq : (z == 1) ? Wk : (z == 2) ? Wv : Wo;
  half_t* dst      = (z == 0) ? WqT : (z == 1) ? WkT : (z == 2) ? WvT : WoT;
  const int R = (z == 1 || z == 2) ? CTXD : CD;
  const int r0 = blockIdx.y * 64, c0 = blockIdx.x * 64;
  if (r0 >= R) return;
  const int t = threadIdx.x;
  const int rr = t >> 4, cc = (t & 15) * 4;
#pragma unroll
  for (int j = 0; j < 4; ++j) {
    const int r = rr + j * 16;
    float4 v = *reinterpret_cast<const float4*>(&src[(long)(r0 + r) * CD + c0 + cc]);
    tile[cc + 0][r] = (half_t)v.x;
    tile[cc + 1][r] = (half_t)v.y;
    tile[cc + 2][r] = (half_t)v.z;
    tile[cc + 3][r] = (half_t)v.w;
  }
  __syncthreads();
  const int cr = t >> 2, rc = (t & 3) * 16;
  half_t* dp = &dst[(long)(c0 + cr) * R + r0 + rc];
  *reinterpret_cast<int4*>(dp)     = *reinterpret_cast<const int4*>(&tile[cr][rc]);
  *reinterpret_cast<int4*>(dp + 8) = *reinterpret_cast<const int4*>(&tile[cr][rc + 8]);
}

// ---------------- K/V projection ----------------
// ctx (B,77,768) f32 @ WT(640,768)^T + bias ->
//   kv==0: k_ws  (B, 8, 80, 96)  [t][dd]
//   kv==1: vT_ws (B, 8, 80, 96)  [dd][t]
// Pad columns [80,96) zeroed here (block x==0 of each (b,kv)).
__global__ __launch_bounds__(256) void kv_kernel(
    const float* __restrict__ ctx,
    const half_t* __restrict__ WkT, const half_t* __restrict__ WvT,
    const float* __restrict__ bk, const float* __restrict__ bv,
    half_t* __restrict__ k_ws, half_t* __restrict__ vT_ws) {
  __shared__ half_t C_sm[80][32];
  const int n0 = blockIdx.x * 64;
  const int b  = blockIdx.y;
  const int kv = blockIdx.z;
  const half_t* WT  = kv ? WvT : WkT;
  const float* bias = kv ? bv : bk;
  const int tid = threadIdx.x;
  const int wave = tid >> 6, lane = tid & 63, g = lane >> 4, ln = lane & 15;

  if (blockIdx.x == 0) {
    half_t* dst = kv ? vT_ws : k_ws;
    for (int i = tid; i < 1280; i += 256) {   // 8h * 80rows * 2 chunks
      const int hh = i / 160, rr = i % 160;
      half_t* p = dst + (((long)b * NH + hh) * 80 + (rr >> 1)) * DP + 80 + (rr & 1) * 8;
      *reinterpret_cast<int4*>(p) = make_int4(0, 0, 0, 0);
    }
  }

  f32x4 acc[5];
#pragma unroll
  for (int i = 0; i < 5; ++i) acc[i] = (f32x4){0.f, 0.f, 0.f, 0.f};

  for (int k0 = 0; k0 < CTXD; k0 += 32) {
    if (k0) __syncthreads();
    for (int i = tid; i < 320; i += 256) {
      const int r = i >> 2, c8 = (i & 3) * 8;
      f16x8 hv = {0, 0, 0, 0, 0, 0, 0, 0};
      if (r < TT) {
        const float* cp = ctx + ((long)b * TT + r) * CTXD + k0 + c8;
        float4 c0v = *reinterpret_cast<const float4*>(cp);
        float4 c1v = *reinterpret_cast<const float4*>(cp + 4);
        hv[0] = (half_t)c0v.x; hv[1] = (half_t)c0v.y;
        hv[2] = (half_t)c0v.z; hv[3] = (half_t)c0v.w;
        hv[4] = (half_t)c1v.x; hv[5] = (half_t)c1v.y;
        hv[6] = (half_t)c1v.z; hv[7] = (half_t)c1v.w;
      }
      *reinterpret_cast<f16x8*>(&C_sm[r][c8]) = hv;
    }
    __syncthreads();
    f16x8 bfr = *reinterpret_cast<const f16x8*>(
        &WT[(long)(n0 + wave * 16 + ln) * CTXD + k0 + g * 8]);
#pragma unroll
    for (int mt = 0; mt < 5; ++mt) {
      f16x8 afr = *reinterpret_cast<const f16x8*>(&C_sm[mt * 16 + ln][g * 8]);
      acc[mt] = __builtin_amdgcn_mfma_f32_16x16x32_f16(afr, bfr, acc[mt], 0, 0, 0);
    }
  }

  const int n = n0 + wave * 16 + ln;
  const float bsv = bias[n];
  const int h = n / DH, dd = n % DH;
  if (kv == 0) {
#pragma unroll
    for (int mt = 0; mt < 5; ++mt)
#pragma unroll
      for (int r = 0; r < 4; ++r) {
        const int t = mt * 16 + g * 4 + r;
        k_ws[(((long)b * NH + h) * 80 + t) * DP + dd] = (half_t)(acc[mt][r] + bsv);
      }
  } else {
#pragma unroll
    for (int mt = 0; mt < 5; ++mt) {
      const int t0 = mt * 16 + g * 4;
      f16x4 v4;
#pragma unroll
      for (int r = 0; r < 4; ++r) v4[r] = (half_t)(acc[mt][r] + bsv);
      *reinterpret_cast<f16x4*>(&vT_ws[(((long)b * NH + h) * 80 + dd) * DP + t0]) = v4;
    }
  }
}

// ---------------- panel GEMM, 256x128 tile, PHASE-SPLIT schedule ------------
// Best-verified GEMM (rounds 5-9: 95-97 us, MfmaUtil 23, conflicts 0).
// Triple buffer, 2 phases of 8 MFMA per BK=32 step, counted vmcnt(3) once
// per step, setprio around MFMA. Occupancy is register-bound at 2 blocks/CU
// (rounds 7-8); schedule/tile/buffering levers exhausted (rounds 0-8).
template <int EPI>
__global__ __launch_bounds__(512, 4) void pgemm8_kernel(
    const half_t* __restrict__ A, const half_t* __restrict__ BT,
    const float* __restrict__ bias, void* __restrict__ outp) {
  __shared__ __align__(16) half_t A_sm[3][256 * 32];   // 48 KB
  __shared__ __align__(16) half_t B_sm[3][128 * 32];   // 24 KB
  const int tid = threadIdx.x;
  const int lane = tid & 63, wave = tid >> 6;   // wave 0..7
  const int g = lane >> 4, ln = lane & 15;
  const int wm = wave >> 1, wn = wave & 1;      // 4 x 2 wave grid

  int panel, nblk;
  xcd_panel_map(blockIdx.x, panel, nblk);
  const long m0 = (long)panel * 256;
  const int n0 = nblk * 128;

  // staging: lane l -> row wave*16+(l>>2), phys slot l&3 holds source
  // k-chunk (l&3)^((l>>3)&3)  [proven 0-conflict, rounds 0-9]
  const int srow = tid >> 2;                                  // 0..127
  const int sk8 = ((tid & 3) ^ ((tid >> 3) & 3)) * 8;
  const half_t* ag0 = A + (m0 + srow) * CD + sk8;
  const half_t* ag1 = ag0 + 128 * CD;                         // rows 128..255
  const half_t* bg0 = BT + (long)(n0 + srow) * CD + sk8;

  // fragment-read slot (loop-invariant): g ^ ((ln>>1)&3)
  const int rs8 = (g ^ ((ln >> 1) & 3)) * 8;

  f32x4 acc[4][4];
#pragma unroll
  for (int i = 0; i < 4; ++i)
#pragma unroll
    for (int j = 0; j < 4; ++j) acc[i][j] = (f32x4){0.f, 0.f, 0.f, 0.f};

#define STAGE_A(buf, kt)                                              \
  do {                                                                \
    GLOAD16(ag0 + (long)(kt) * 32, &A_sm[buf][wave * 512]);           \
    GLOAD16(ag1 + (long)(kt) * 32, &A_sm[buf][4096 + wave * 512]);    \
  } while (0)
#define STAGE_B(buf, kt)                                              \
  GLOAD16(bg0 + (long)(kt) * 32, &B_sm[buf][wave * 512])

#define READ_A2(dst0, dst1, buf, mi0)                                 \
  do {                                                                \
    dst0 = *reinterpret_cast<const f16x8*>(                           \
        &A_sm[buf][(wm * 64 + (mi0) * 16 + ln) * 32 + rs8]);          \
    dst1 = *reinterpret_cast<const f16x8*>(                           \
        &A_sm[buf][(wm * 64 + ((mi0) + 1) * 16 + ln) * 32 + rs8]);    \
  } while (0)
#define READ_B4(bf, buf)                                              \
  do {                                                                \
    _Pragma("unroll")                                                 \
    for (int ni = 0; ni < 4; ++ni)                                    \
      bf[ni] = *reinterpret_cast<const f16x8*>(                       \
          &B_sm[buf][(wn * 64 + ni * 16 + ln) * 32 + rs8]);           \
  } while (0)

#define MFMA8(a0, a1, bf, mi0)                                        \
  do {                                                                \
    __builtin_amdgcn_s_setprio(1);                                    \
    _Pragma("unroll")                                                 \
    for (int ni = 0; ni < 4; ++ni)                                    \
      acc[mi0][ni] = __builtin_amdgcn_mfma_f32_16x16x32_f16(          \
          a0, bf[ni], acc[mi0][ni], 0, 0, 0);                         \
    _Pragma("unroll")                                                 \
    for (int ni = 0; ni < 4; ++ni)                                    \
      acc[(mi0) + 1][ni] = __builtin_amdgcn_mfma_f32_16x16x32_f16(    \
          a1, bf[ni], acc[(mi0) + 1][ni], 0, 0, 0);                   \
    __builtin_amdgcn_s_setprio(0);                                    \
  } while (0)

#define WAIT_LGKM_FENCE()                                             \
  do {                                                                \
    asm volatile("s_waitcnt lgkmcnt(0)" ::: "memory");                \
    __builtin_amdgcn_sched_barrier(0);                                \
  } while (0)

  // prologue: stage(0), stage(1); drain stage(0) (vmcnt: 6 out -> keep 3)
  STAGE_A(0, 0); STAGE_B(0, 0);
  STAGE_A(1, 1); STAGE_B(1, 1);
  asm volatile("s_waitcnt vmcnt(3)" ::: "memory");
  __builtin_amdgcn_s_barrier();

  const int nk = CD / 32;  // 20
  f16x8 a0, a1, a2, a3, bf[4];
  for (int t = 0; t < nk - 2; ++t) {
    const int cur = t % 3, nxt = (t + 2) % 3;
    // ---- phase 1: reads + A-stage issue, then 8 MFMA (mi 0,1) ----
    READ_A2(a0, a1, cur, 0);
    READ_B4(bf, cur);
    STAGE_A(nxt, t + 2);
    __builtin_amdgcn_s_barrier();
    WAIT_LGKM_FENCE();
    MFMA8(a0, a1, bf, 0);
    __builtin_amdgcn_s_barrier();
    // ---- phase 2: reads + B-stage issue + boundary vmcnt, 8 MFMA (mi 2,3) --
    READ_A2(a2, a3, cur, 2);
    STAGE_B(nxt, t + 2);
    asm volatile("s_waitcnt vmcnt(3)" ::: "memory");   // stage(t+1) arrived
    __builtin_amdgcn_s_barrier();
    WAIT_LGKM_FENCE();
    MFMA8(a2, a3, bf, 2);
    __builtin_amdgcn_s_barrier();
  }
  // t = nk-2: no issue; drain stage(nk-1)
  {
    const int cur = (nk - 2) % 3;
    READ_A2(a0, a1, cur, 0);
    READ_B4(bf, cur);
    __builtin_amdgcn_s_barrier();
    WAIT_LGKM_FENCE();
    MFMA8(a0, a1, bf, 0);
    __builtin_amdgcn_s_barrier();
    READ_A2(a2, a3, cur, 2);
    asm volatile("s_waitcnt vmcnt(0)" ::: "memory");
    __builtin_amdgcn_s_barrier();
    WAIT_LGKM_FENCE();
    MFMA8(a2, a3, bf, 2);
    __builtin_amdgcn_s_barrier();
  }
  // t = nk-1: compute only
  {
    const int cur = (nk - 1) % 3;
    READ_A2(a0, a1, cur, 0);
    READ_B4(bf, cur);
    WAIT_LGKM_FENCE();
    MFMA8(a0, a1, bf, 0);
    READ_A2(a2, a3, cur, 2);
    WAIT_LGKM_FENCE();
    MFMA8(a2, a3, bf, 2);
  }

  if (EPI == 0) {
    half_t* O = (half_t*)outp;
#pragma unroll
    for (int ni = 0; ni < 4; ++ni) {
      const int n = n0 + wn * 64 + ni * 16 + ln;
      const float bvv = bias[n];
#pragma unroll
      for (int mi = 0; mi < 4; ++mi) {
        const long m = m0 + wm * 64 + mi * 16 + g * 4;
        f32x4 v = acc[mi][ni];
#pragma unroll
        for (int r = 0; r < 4; ++r)
          O[(m + r) * CD + n] = (half_t)(v[r] + bvv);
      }
    }
  } else {
    float* O = (float*)outp;
#pragma unroll
    for (int mi = 0; mi < 4; ++mi) {
      const long m = m0 + wm * 64 + mi * 16 + g * 4;
      const long bb = m >> 12;
      const int p = (int)(m & 4095);
#pragma unroll
      for (int ni = 0; ni < 4; ++ni) {
        const int n = n0 + wn * 64 + ni * 16 + ln;
        const float bvv = bias[n];
        f32x4 v = acc[mi][ni];
        float4 o4 = make_float4(v[0] + bvv, v[1] + bvv, v[2] + bvv, v[3] + bvv);
        *reinterpret_cast<float4*>(&O[((bb * CD + n) << 12) + p]) = o4;
      }
    }
  }
#undef STAGE_A
#undef STAGE_B
#undef READ_A2
#undef READ_B4
#undef MFMA8
#undef WAIT_LGKM_FENCE
}

// ---------------- fused attention (512 px / block, 4-tile pipeline) ---------
// Round-10: extend round-9's proven T14 structure from 2 to 4 tiles per
// block. K/V loaded ONCE per block (4x amortized); Q tile i+1's global
// loads are issued BEFORE tile-i compute (sched_barrier(0) pins the issue
// point) so their latency hides under tile-i's 30 MFMA + softmax. Only
// next-tile Q held in regs (12 VGPR). Q staging stays WAVE-PRIVATE (wave w
// touches only its own 16 rows -> per-wave in-order DS pipe, no barriers
// between tiles; validated round 9). Single __syncthreads for K/V.
__global__ __launch_bounds__(512) void attn_kernel(
    const half_t* __restrict__ q_ws, const half_t* __restrict__ k_ws,
    const half_t* __restrict__ vT_ws, half_t* __restrict__ attn_ws) {
  __shared__ half_t K_sm[80][DP];
  __shared__ half_t V_sm[80][DP];
  __shared__ half_t Q_sm[128][DP];  // per-wave 16-row slices; reused per tile
  const int p0 = blockIdx.x * 512;
  const int h  = blockIdx.y;
  const int b  = blockIdx.z;
  const int tid = threadIdx.x, wave = tid >> 6, lane = tid & 63;
  const int g = lane >> 4, ln = lane & 15;

  // ---- K/V: all loads up-front into regs ----
  const int4* kp4 = reinterpret_cast<const int4*>(k_ws  + ((long)b * NH + h) * 80 * DP);
  const int4* vp4 = reinterpret_cast<const int4*>(vT_ws + ((long)b * NH + h) * 80 * DP);
  int4 kr0, kr1, vr0, vr1;
  kr0 = kp4[tid];
  vr0 = vp4[tid];
  const int i2 = tid + 512;
  if (i2 < 960) { kr1 = kp4[i2]; vr1 = vp4[i2]; }

  // Q chunk geometry, wave-private: wave stages its own rows [wave*16,+16)
  // chunk c = lane + j*64 in [0,192): row = wave*16 + c/12, c8 = c%12
  int qr_[3], qc_[3];
#pragma unroll
  for (int j = 0; j < 3; ++j) {
    const int c = lane + j * 64;
    qr_[j] = wave * 16 + c / 12;
    qc_[j] = c % 12;
  }
  const half_t* qbase = q_ws + ((long)(b * HWD + p0)) * CD + h * DH;

  // Q tile0 loads
  int4 qn[3];
#pragma unroll
  for (int j = 0; j < 3; ++j) {
    qn[j] = make_int4(0, 0, 0, 0);
    if (qc_[j] < 10)
      qn[j] = *reinterpret_cast<const int4*>(
          qbase + (long)qr_[j] * CD + qc_[j] * 8);
  }

  // ---- LDS writes: K/V (shared) + Q tile0 (wave-private) ----
  reinterpret_cast<int4*>(K_sm)[tid] = kr0;
  reinterpret_cast<int4*>(V_sm)[tid] = vr0;
  if (i2 < 960) {
    reinterpret_cast<int4*>(K_sm)[i2] = kr1;
    reinterpret_cast<int4*>(V_sm)[i2] = vr1;
  }
#pragma unroll
  for (int j = 0; j < 3; ++j)
    *reinterpret_cast<int4*>(&Q_sm[qr_[j]][qc_[j] * 8]) = qn[j];
  __syncthreads();   // K/V visible to all waves (also drains Q0 writes)

  const float sc = 0.11180339887498949f;   // 80^-0.5

#define TILE_COMPUTE(toff)                                                     \
  do {                                                                         \
    f32x4 s[5];                                                                \
    _Pragma("unroll") for (int i = 0; i < 5; ++i)                              \
        s[i] = (f32x4){0.f, 0.f, 0.f, 0.f};                                    \
    _Pragma("unroll") for (int ks = 0; ks < 3; ++ks) {                         \
      f16x8 bq = *reinterpret_cast<const f16x8*>(                              \
          &Q_sm[wave * 16 + ln][ks * 32 + g * 8]);                             \
      _Pragma("unroll") for (int mt = 0; mt < 5; ++mt) {                       \
        f16x8 ak = *reinterpret_cast<const f16x8*>(                            \
            &K_sm[mt * 16 + ln][ks * 32 + g * 8]);                             \
        s[mt] = __builtin_amdgcn_mfma_f32_16x16x32_f16(ak, bq, s[mt], 0, 0, 0);\
      }                                                                        \
    }                                                                          \
    float mx = -1e30f;                                                         \
    _Pragma("unroll") for (int mt = 0; mt < 5; ++mt)                           \
      _Pragma("unroll") for (int r = 0; r < 4; ++r) {                          \
        const int t = mt * 16 + g * 4 + r;                                     \
        const float v = s[mt][r] * sc;                                         \
        s[mt][r] = v;                                                          \
        if (t < TT) mx = fmaxf(mx, v);                                         \
      }                                                                        \
    mx = fmaxf(mx, __shfl_xor(mx, 16));                                        \
    mx = fmaxf(mx, __shfl_xor(mx, 32));                                        \
    float e[5][4];                                                             \
    float sum = 0.f;                                                           \
    _Pragma("unroll") for (int mt = 0; mt < 5; ++mt)                           \
      _Pragma("unroll") for (int r = 0; r < 4; ++r) {                          \
        const int t = mt * 16 + g * 4 + r;                                     \
        float ev = 0.f;                                                        \
        if (t < TT) { ev = __expf(s[mt][r] - mx); sum += ev; }                 \
        e[mt][r] = ev;                                                         \
      }                                                                        \
    sum += __shfl_xor(sum, 16);                                                \
    sum += __shfl_xor(sum, 32);                                                \
    const float inv = 1.f / sum;                                               \
    _Pragma("unroll") for (int mt = 0; mt < 5; ++mt) {                         \
      f16x4 pv;                                                                \
      _Pragma("unroll") for (int r = 0; r < 4; ++r)                            \
        pv[r] = (half_t)(e[mt][r] * inv);                                      \
      *reinterpret_cast<f16x4*>(&Q_sm[wave * 16 + ln][mt * 16 + g * 4]) = pv;  \
    }                                                                          \
    f32x4 o[5];                                                                \
    _Pragma("unroll") for (int i = 0; i < 5; ++i)                              \
        o[i] = (f32x4){0.f, 0.f, 0.f, 0.f};                                    \
    _Pragma("unroll") for (int ks = 0; ks < 3; ++ks) {                         \
      f16x8 bp = *reinterpret_cast<const f16x8*>(                              \
          &Q_sm[wave * 16 + ln][ks * 32 + g * 8]);                             \
      _Pragma("unroll") for (int mt = 0; mt < 5; ++mt) {                       \
        f16x8 av = *reinterpret_cast<const f16x8*>(                            \
            &V_sm[mt * 16 + ln][ks * 32 + g * 8]);                             \
        o[mt] = __builtin_amdgcn_mfma_f32_16x16x32_f16(av, bp, o[mt], 0, 0, 0);\
      }                                                                        \
    }                                                                          \
    half_t* op = attn_ws +                                                     \
        ((long)(b * HWD + p0 + (toff) + wave * 16 + ln)) * CD + h * DH;        \
    _Pragma("unroll") for (int mt = 0; mt < 5; ++mt) {                         \
      f16x4 v4;                                                                \
      _Pragma("unroll") for (int r = 0; r < 4; ++r)                            \
        v4[r] = (half_t)o[mt][r];                                              \
      *reinterpret_cast<f16x4*>(&op[mt * 16 + g * 4]) = v4;                    \
    }                                                                          \
  } while (0)

#pragma unroll
  for (int tile = 0; tile < 4; ++tile) {
    // issue next tile's Q loads BEFORE compute; sched_barrier pins issue
    if (tile < 3) {
#pragma unroll
      for (int j = 0; j < 3; ++j) {
        qn[j] = make_int4(0, 0, 0, 0);
        if (qc_[j] < 10)
          qn[j] = *reinterpret_cast<const int4*>(
              qbase + (long)((tile + 1) * 128 + qr_[j]) * CD + qc_[j] * 8);
      }
      __builtin_amdgcn_sched_barrier(0);   // loads issued before compute
    }
    TILE_COMPUTE(tile * 128);
    if (tile < 3) {
      // stage Q tile+1 (wave-private; follows this wave's PV reads in the
      // in-order DS pipe, so no barrier needed)
#pragma unroll
      for (int j = 0; j < 3; ++j)
        *reinterpret_cast<int4*>(&Q_sm[qr_[j]][qc_[j] * 8]) = qn[j];
      asm volatile("s_waitcnt lgkmcnt(0)" ::: "memory");
      __builtin_amdgcn_sched_barrier(0);
    }
  }
#undef TILE_COMPUTE
}

// ---------------- launch ----------------
extern "C" void kernel_launch(void* const* d_in, const int* in_sizes, int n_in,
                              void* d_out, int out_size, void* d_ws, size_t ws_size,
                              hipStream_t stream) {
  const float* x   = (const float*)d_in[0];
  const float* ctx = (const float*)d_in[1];
  const float* Wq  = (const float*)d_in[2];
  const float* bq  = (const float*)d_in[3];
  const float* Wk  = (const float*)d_in[4];
  const float* bk  = (const float*)d_in[5];
  const float* Wv  = (const float*)d_in[6];
  const float* bv  = (const float*)d_in[7];
  const float* Wo  = (const float*)d_in[8];
  const float* bo  = (const float*)d_in[9];
  float* out = (float*)d_out;

  char* ws = (char*)d_ws;
  size_t off = 0;
  auto alloc = [&](size_t bytes) {
    void* p = ws + off;
    off += (bytes + 255) & ~(size_t)255;
    return p;
  };
  half_t* WqT  = (half_t*)alloc((size_t)CD * CD * 2);
  half_t* WkT  = (half_t*)alloc((size_t)CD * CTXD * 2);
  half_t* WvT  = (half_t*)alloc((size_t)CD * CTXD * 2);
  half_t* WoT  = (half_t*)alloc((size_t)CD * CD * 2);
  half_t* kws  = (half_t*)alloc((size_t)NB * NH * 80 * DP * 2);
  half_t* vTws = (half_t*)alloc((size_t)NB * NH * 80 * DP * 2);
  half_t* xt   = (half_t*)alloc((size_t)NB * HWD * CD * 2);
  half_t* q    = (half_t*)alloc((size_t)NB * HWD * CD * 2);
  half_t* attn = xt;   // xt dead after pgemm8<0>; alias

  // weight transposes (f32 -> f16)
  wtrans_kernel<<<dim3(CD / 64, CTXD / 64, 4), 256, 0, stream>>>(
      Wq, Wk, Wv, Wo, WqT, WkT, WvT, WoT);

  // K/V projection (+ pad zeroing)
  kv_kernel<<<dim3(CD / 64, NB, 2), 256, 0, stream>>>(ctx, WkT, WvT, bk, bv, kws, vTws);

  // x transpose + convert
  xpose_kernel<<<dim3(HWD / 64, CD / 64, NB), 256, 0, stream>>>(x, xt);

  // Q projection (256x128 tiles, phase-split schedule)
  pgemm8_kernel<0><<<(CD / 128) * ((NB * HWD) / 256), 512, 0, stream>>>(
      xt, WqT, bq, q);

  // fused attention (512 px / block, 4-tile pipeline)
  attn_kernel<<<dim3(HWD / 512, NH, NB), 512, 0, stream>>>(q, kws, vTws, attn);

  // O projection (256x128 tiles, phase-split schedule)
  pgemm8_kernel<1><<<(CD / 128) * ((NB * HWD) / 256), 512, 0, stream>>>(
      attn, WoT, bo, out);
}

// Round 11
// 293.387 us; speedup vs baseline: 2.7437x; 1.0028x over previous
//
#include <hip/hip_runtime.h>
#include <hip/hip_fp16.h>

typedef _Float16 half_t;
typedef _Float16 f16x8 __attribute__((ext_vector_type(8)));
typedef _Float16 f16x4 __attribute__((ext_vector_type(4)));
typedef float f32x4 __attribute__((ext_vector_type(4)));

// problem constants
#define NB   16
#define CD   640
#define HWD  4096
#define TT   77
#define CTXD 768
#define NH   8
#define DH   80
#define DP   96   // padded d / padded T for the attention kernel

#define GLOAD16(gp, lp)                                                        \
  __builtin_amdgcn_global_load_lds(                                            \
      (const __attribute__((address_space(1))) void*)(gp),                     \
      (__attribute__((address_space(3))) void*)(lp), 16, 0, 0)

// XCD-locality swizzle: 5 n-blocks of one 256-row m-panel -> same XCD.
// grid = 1280 = 8 XCD * 160 slots; 256 panels (%8==0) -> bijective.
__device__ inline void xcd_panel_map(int j, int& panel, int& nblk) {
  const int xcd = j & 7, slot = j >> 3;
  panel = (slot / 5) * 8 + xcd;
  nblk = slot % 5;
}

// ---------------- x transpose + f32->f16 convert ----------------
// x (B, 640, 4096) f32 -> xt (B, 4096, 640) f16.  At BW roofline:
// 252 MB traffic ~= 40 us.
__global__ __launch_bounds__(256) void xpose_kernel(
    const float* __restrict__ x, half_t* __restrict__ xt) {
  __shared__ half_t tile[64][72];
  const float* s = x + (long)blockIdx.z * CD * HWD;
  half_t* d = xt + (long)blockIdx.z * HWD * CD;
  const int r0 = blockIdx.y * 64;   // channel
  const int c0 = blockIdx.x * 64;   // pixel
  const int t = threadIdx.x;
  const int rr = t >> 4, cc = (t & 15) * 4;
#pragma unroll
  for (int j = 0; j < 4; ++j) {
    const int r = rr + j * 16;
    float4 v = *reinterpret_cast<const float4*>(&s[(long)(r0 + r) * HWD + c0 + cc]);
    tile[cc + 0][r] = (half_t)v.x;
    tile[cc + 1][r] = (half_t)v.y;
    tile[cc + 2][r] = (half_t)v.z;
    tile[cc + 3][r] = (half_t)v.w;
  }
  __syncthreads();
  const int cr = t >> 2, rc = (t & 3) * 16;
  half_t* dp = &d[(long)(c0 + cr) * CD + r0 + rc];
  *reinterpret_cast<int4*>(dp)     = *reinterpret_cast<const int4*>(&tile[cr][rc]);
  *reinterpret_cast<int4*>(dp + 8) = *reinterpret_cast<const int4*>(&tile[cr][rc + 8]);
}

// ---------------- merged weight transpose + f32->f16 convert ----------------
__global__ __launch_bounds__(256) void wtrans_kernel(
    const float* __restrict__ Wq, const float* __restrict__ Wk,
    const float* __restrict__ Wv, const float* __restrict__ Wo,
    half_t* __restrict__ WqT, half_t* __restrict__ WkT,
    half_t* __restrict__ WvT, half_t* __restrict__ WoT) {
  __shared__ half_t tile[64][72];
  const int z = blockIdx.z;
  const float* src = (z == 0) ? Wq : (z == 1) ? Wk : (z == 2) ? Wv : Wo;
  half_t* dst      = (z == 0) ? WqT : (z == 1) ? WkT : (z == 2) ? WvT : WoT;
  const int R = (z == 1 || z == 2) ? CTXD : CD;
  const int r0 = blockIdx.y * 64, c0 = blockIdx.x * 64;
  if (r0 >= R) return;
  const int t = threadIdx.x;
  const int rr = t >> 4, cc = (t & 15) * 4;
#pragma unroll
  for (int j = 0; j < 4; ++j) {
    const int r = rr + j * 16;
    float4 v = *reinterpret_cast<const float4*>(&src[(long)(r0 + r) * CD + c0 + cc]);
    tile[cc + 0][r] = (half_t)v.x;
    tile[cc + 1][r] = (half_t)v.y;
    tile[cc + 2][r] = (half_t)v.z;
    tile[cc + 3][r] = (half_t)v.w;
  }
  __syncthreads();
  const int cr = t >> 2, rc = (t & 3) * 16;
  half_t* dp = &dst[(long)(c0 + cr) * R + r0 + rc];
  *reinterpret_cast<int4*>(dp)     = *reinterpret_cast<const int4*>(&tile[cr][rc]);
  *reinterpret_cast<int4*>(dp + 8) = *reinterpret_cast<const int4*>(&tile[cr][rc + 8]);
}

// ---------------- K/V projection ----------------
// ctx (B,77,768) f32 @ WT(640,768)^T + bias ->
//   kv==0: k_ws  (B, 8, 80, 96)  [t][dd]
//   kv==1: vT_ws (B, 8, 80, 96)  [dd][t]
// Pad columns [80,96) zeroed here (block x==0 of each (b,kv)).
__global__ __launch_bounds__(256) void kv_kernel(
    const float* __restrict__ ctx,
    const half_t* __restrict__ WkT, const half_t* __restrict__ WvT,
    const float* __restrict__ bk, const float* __restrict__ bv,
    half_t* __restrict__ k_ws, half_t* __restrict__ vT_ws) {
  __shared__ half_t C_sm[80][32];
  const int n0 = blockIdx.x * 64;
  const int b  = blockIdx.y;
  const int kv = blockIdx.z;
  const half_t* WT  = kv ? WvT : WkT;
  const float* bias = kv ? bv : bk;
  const int tid = threadIdx.x;
  const int wave = tid >> 6, lane = tid & 63, g = lane >> 4, ln = lane & 15;

  if (blockIdx.x == 0) {
    half_t* dst = kv ? vT_ws : k_ws;
    for (int i = tid; i < 1280; i += 256) {   // 8h * 80rows * 2 chunks
      const int hh = i / 160, rr = i % 160;
      half_t* p = dst + (((long)b * NH + hh) * 80 + (rr >> 1)) * DP + 80 + (rr & 1) * 8;
      *reinterpret_cast<int4*>(p) = make_int4(0, 0, 0, 0);
    }
  }

  f32x4 acc[5];
#pragma unroll
  for (int i = 0; i < 5; ++i) acc[i] = (f32x4){0.f, 0.f, 0.f, 0.f};

  for (int k0 = 0; k0 < CTXD; k0 += 32) {
    if (k0) __syncthreads();
    for (int i = tid; i < 320; i += 256) {
      const int r = i >> 2, c8 = (i & 3) * 8;
      f16x8 hv = {0, 0, 0, 0, 0, 0, 0, 0};
      if (r < TT) {
        const float* cp = ctx + ((long)b * TT + r) * CTXD + k0 + c8;
        float4 c0v = *reinterpret_cast<const float4*>(cp);
        float4 c1v = *reinterpret_cast<const float4*>(cp + 4);
        hv[0] = (half_t)c0v.x; hv[1] = (half_t)c0v.y;
        hv[2] = (half_t)c0v.z; hv[3] = (half_t)c0v.w;
        hv[4] = (half_t)c1v.x; hv[5] = (half_t)c1v.y;
        hv[6] = (half_t)c1v.z; hv[7] = (half_t)c1v.w;
      }
      *reinterpret_cast<f16x8*>(&C_sm[r][c8]) = hv;
    }
    __syncthreads();
    f16x8 bfr = *reinterpret_cast<const f16x8*>(
        &WT[(long)(n0 + wave * 16 + ln) * CTXD + k0 + g * 8]);
#pragma unroll
    for (int mt = 0; mt < 5; ++mt) {
      f16x8 afr = *reinterpret_cast<const f16x8*>(&C_sm[mt * 16 + ln][g * 8]);
      acc[mt] = __builtin_amdgcn_mfma_f32_16x16x32_f16(afr, bfr, acc[mt], 0, 0, 0);
    }
  }

  const int n = n0 + wave * 16 + ln;
  const float bsv = bias[n];
  const int h = n / DH, dd = n % DH;
  if (kv == 0) {
#pragma unroll
    for (int mt = 0; mt < 5; ++mt)
#pragma unroll
      for (int r = 0; r < 4; ++r) {
        const int t = mt * 16 + g * 4 + r;
        k_ws[(((long)b * NH + h) * 80 + t) * DP + dd] = (half_t)(acc[mt][r] + bsv);
      }
  } else {
#pragma unroll
    for (int mt = 0; mt < 5; ++mt) {
      const int t0 = mt * 16 + g * 4;
      f16x4 v4;
#pragma unroll
      for (int r = 0; r < 4; ++r) v4[r] = (half_t)(acc[mt][r] + bsv);
      *reinterpret_cast<f16x4*>(&vT_ws[(((long)b * NH + h) * 80 + dd) * DP + t0]) = v4;
    }
  }
}

// ---------------- panel GEMM, 256x128 tile, PHASE-SPLIT schedule ------------
// Best-verified GEMM (rounds 5-10: 95-97 us, MfmaUtil 23, conflicts 0).
// Triple buffer, 2 phases of 8 MFMA per BK=32 step, counted vmcnt(3) once
// per step, setprio around MFMA. Occupancy is register-bound at 2 blocks/CU
// (rounds 7-8); schedule/tile/buffering levers exhausted (rounds 0-8).
template <int EPI>
__global__ __launch_bounds__(512, 4) void pgemm8_kernel(
    const half_t* __restrict__ A, const half_t* __restrict__ BT,
    const float* __restrict__ bias, void* __restrict__ outp) {
  __shared__ __align__(16) half_t A_sm[3][256 * 32];   // 48 KB
  __shared__ __align__(16) half_t B_sm[3][128 * 32];   // 24 KB
  const int tid = threadIdx.x;
  const int lane = tid & 63, wave = tid >> 6;   // wave 0..7
  const int g = lane >> 4, ln = lane & 15;
  const int wm = wave >> 1, wn = wave & 1;      // 4 x 2 wave grid

  int panel, nblk;
  xcd_panel_map(blockIdx.x, panel, nblk);
  const long m0 = (long)panel * 256;
  const int n0 = nblk * 128;

  // staging: lane l -> row wave*16+(l>>2), phys slot l&3 holds source
  // k-chunk (l&3)^((l>>3)&3)  [proven 0-conflict, rounds 0-10]
  const int srow = tid >> 2;                                  // 0..127
  const int sk8 = ((tid & 3) ^ ((tid >> 3) & 3)) * 8;
  const half_t* ag0 = A + (m0 + srow) * CD + sk8;
  const half_t* ag1 = ag0 + 128 * CD;                         // rows 128..255
  const half_t* bg0 = BT + (long)(n0 + srow) * CD + sk8;

  // fragment-read slot (loop-invariant): g ^ ((ln>>1)&3)
  const int rs8 = (g ^ ((ln >> 1) & 3)) * 8;

  f32x4 acc[4][4];
#pragma unroll
  for (int i = 0; i < 4; ++i)
#pragma unroll
    for (int j = 0; j < 4; ++j) acc[i][j] = (f32x4){0.f, 0.f, 0.f, 0.f};

#define STAGE_A(buf, kt)                                              \
  do {                                                                \
    GLOAD16(ag0 + (long)(kt) * 32, &A_sm[buf][wave * 512]);           \
    GLOAD16(ag1 + (long)(kt) * 32, &A_sm[buf][4096 + wave * 512]);    \
  } while (0)
#define STAGE_B(buf, kt)                                              \
  GLOAD16(bg0 + (long)(kt) * 32, &B_sm[buf][wave * 512])

#define READ_A2(dst0, dst1, buf, mi0)                                 \
  do {                                                                \
    dst0 = *reinterpret_cast<const f16x8*>(                           \
        &A_sm[buf][(wm * 64 + (mi0) * 16 + ln) * 32 + rs8]);          \
    dst1 = *reinterpret_cast<const f16x8*>(                           \
        &A_sm[buf][(wm * 64 + ((mi0) + 1) * 16 + ln) * 32 + rs8]);    \
  } while (0)
#define READ_B4(bf, buf)                                              \
  do {                                                                \
    _Pragma("unroll")                                                 \
    for (int ni = 0; ni < 4; ++ni)                                    \
      bf[ni] = *reinterpret_cast<const f16x8*>(                       \
          &B_sm[buf][(wn * 64 + ni * 16 + ln) * 32 + rs8]);           \
  } while (0)

#define MFMA8(a0, a1, bf, mi0)                                        \
  do {                                                                \
    __builtin_amdgcn_s_setprio(1);                                    \
    _Pragma("unroll")                                                 \
    for (int ni = 0; ni < 4; ++ni)                                    \
      acc[mi0][ni] = __builtin_amdgcn_mfma_f32_16x16x32_f16(          \
          a0, bf[ni], acc[mi0][ni], 0, 0, 0);                         \
    _Pragma("unroll")                                                 \
    for (int ni = 0; ni < 4; ++ni)                                    \
      acc[(mi0) + 1][ni] = __builtin_amdgcn_mfma_f32_16x16x32_f16(    \
          a1, bf[ni], acc[(mi0) + 1][ni], 0, 0, 0);                   \
    __builtin_amdgcn_s_setprio(0);                                    \
  } while (0)

#define WAIT_LGKM_FENCE()                                             \
  do {                                                                \
    asm volatile("s_waitcnt lgkmcnt(0)" ::: "memory");                \
    __builtin_amdgcn_sched_barrier(0);                                \
  } while (0)

  // prologue: stage(0), stage(1); drain stage(0) (vmcnt: 6 out -> keep 3)
  STAGE_A(0, 0); STAGE_B(0, 0);
  STAGE_A(1, 1); STAGE_B(1, 1);
  asm volatile("s_waitcnt vmcnt(3)" ::: "memory");
  __builtin_amdgcn_s_barrier();

  const int nk = CD / 32;  // 20
  f16x8 a0, a1, a2, a3, bf[4];
  for (int t = 0; t < nk - 2; ++t) {
    const int cur = t % 3, nxt = (t + 2) % 3;
    // ---- phase 1: reads + A-stage issue, then 8 MFMA (mi 0,1) ----
    READ_A2(a0, a1, cur, 0);
    READ_B4(bf, cur);
    STAGE_A(nxt, t + 2);
    __builtin_amdgcn_s_barrier();
    WAIT_LGKM_FENCE();
    MFMA8(a0, a1, bf, 0);
    __builtin_amdgcn_s_barrier();
    // ---- phase 2: reads + B-stage issue + boundary vmcnt, 8 MFMA (mi 2,3) --
    READ_A2(a2, a3, cur, 2);
    STAGE_B(nxt, t + 2);
    asm volatile("s_waitcnt vmcnt(3)" ::: "memory");   // stage(t+1) arrived
    __builtin_amdgcn_s_barrier();
    WAIT_LGKM_FENCE();
    MFMA8(a2, a3, bf, 2);
    __builtin_amdgcn_s_barrier();
  }
  // t = nk-2: no issue; drain stage(nk-1)
  {
    const int cur = (nk - 2) % 3;
    READ_A2(a0, a1, cur, 0);
    READ_B4(bf, cur);
    __builtin_amdgcn_s_barrier();
    WAIT_LGKM_FENCE();
    MFMA8(a0, a1, bf, 0);
    __builtin_amdgcn_s_barrier();
    READ_A2(a2, a3, cur, 2);
    asm volatile("s_waitcnt vmcnt(0)" ::: "memory");
    __builtin_amdgcn_s_barrier();
    WAIT_LGKM_FENCE();
    MFMA8(a2, a3, bf, 2);
    __builtin_amdgcn_s_barrier();
  }
  // t = nk-1: compute only
  {
    const int cur = (nk - 1) % 3;
    READ_A2(a0, a1, cur, 0);
    READ_B4(bf, cur);
    WAIT_LGKM_FENCE();
    MFMA8(a0, a1, bf, 0);
    READ_A2(a2, a3, cur, 2);
    WAIT_LGKM_FENCE();
    MFMA8(a2, a3, bf, 2);
  }

  if (EPI == 0) {
    half_t* O = (half_t*)outp;
#pragma unroll
    for (int ni = 0; ni < 4; ++ni) {
      const int n = n0 + wn * 64 + ni * 16 + ln;
      const float bvv = bias[n];
#pragma unroll
      for (int mi = 0; mi < 4; ++mi) {
        const long m = m0 + wm * 64 + mi * 16 + g * 4;
        f32x4 v = acc[mi][ni];
#pragma unroll
        for (int r = 0; r < 4; ++r)
          O[(m + r) * CD + n] = (half_t)(v[r] + bvv);
      }
    }
  } else {
    float* O = (float*)outp;
#pragma unroll
    for (int mi = 0; mi < 4; ++mi) {
      const long m = m0 + wm * 64 + mi * 16 + g * 4;
      const long bb = m >> 12;
      const int p = (int)(m & 4095);
#pragma unroll
      for (int ni = 0; ni < 4; ++ni) {
        const int n = n0 + wn * 64 + ni * 16 + ln;
        const float bvv = bias[n];
        f32x4 v = acc[mi][ni];
        float4 o4 = make_float4(v[0] + bvv, v[1] + bvv, v[2] + bvv, v[3] + bvv);
        *reinterpret_cast<float4*>(&O[((bb * CD + n) << 12) + p]) = o4;
      }
    }
  }
#undef STAGE_A
#undef STAGE_B
#undef READ_A2
#undef READ_B4
#undef MFMA8
#undef WAIT_LGKM_FENCE
}

// ---------------- fused attention (1024 px / block, 8-tile pipeline) --------
// Round-11: round-10's proven T14 structure extended to 8 tiles/block
// (K/V refetch 61->15 MB; grid 512 = exactly 2 blocks/CU), plus T5
// setprio around the MFMA clusters (catalog m191: +4-7% on attn when
// co-resident blocks progress independently -- exactly this regime).
// Q tile i+1's global loads issue BEFORE tile-i compute (sched_barrier
// pins the issue point); only next-tile Q in registers (12 VGPR).
// Q staging WAVE-PRIVATE (in-order per-wave DS pipe, no inter-tile
// barriers; validated rounds 9-10). Single __syncthreads for K/V.
__global__ __launch_bounds__(512) void attn_kernel(
    const half_t* __restrict__ q_ws, const half_t* __restrict__ k_ws,
    const half_t* __restrict__ vT_ws, half_t* __restrict__ attn_ws) {
  __shared__ half_t K_sm[80][DP];
  __shared__ half_t V_sm[80][DP];
  __shared__ half_t Q_sm[128][DP];  // per-wave 16-row slices; reused per tile
  const int p0 = blockIdx.x * 1024;
  const int h  = blockIdx.y;
  const int b  = blockIdx.z;
  const int tid = threadIdx.x, wave = tid >> 6, lane = tid & 63;
  const int g = lane >> 4, ln = lane & 15;

  // ---- K/V: all loads up-front into regs ----
  const int4* kp4 = reinterpret_cast<const int4*>(k_ws  + ((long)b * NH + h) * 80 * DP);
  const int4* vp4 = reinterpret_cast<const int4*>(vT_ws + ((long)b * NH + h) * 80 * DP);
  int4 kr0, kr1, vr0, vr1;
  kr0 = kp4[tid];
  vr0 = vp4[tid];
  const int i2 = tid + 512;
  if (i2 < 960) { kr1 = kp4[i2]; vr1 = vp4[i2]; }

  // Q chunk geometry, wave-private: wave stages its own rows [wave*16,+16)
  // chunk c = lane + j*64 in [0,192): row = wave*16 + c/12, c8 = c%12
  int qr_[3], qc_[3];
#pragma unroll
  for (int j = 0; j < 3; ++j) {
    const int c = lane + j * 64;
    qr_[j] = wave * 16 + c / 12;
    qc_[j] = c % 12;
  }
  const half_t* qbase = q_ws + ((long)(b * HWD + p0)) * CD + h * DH;

  // Q tile0 loads
  int4 qn[3];
#pragma unroll
  for (int j = 0; j < 3; ++j) {
    qn[j] = make_int4(0, 0, 0, 0);
    if (qc_[j] < 10)
      qn[j] = *reinterpret_cast<const int4*>(
          qbase + (long)qr_[j] * CD + qc_[j] * 8);
  }

  // ---- LDS writes: K/V (shared) + Q tile0 (wave-private) ----
  reinterpret_cast<int4*>(K_sm)[tid] = kr0;
  reinterpret_cast<int4*>(V_sm)[tid] = vr0;
  if (i2 < 960) {
    reinterpret_cast<int4*>(K_sm)[i2] = kr1;
    reinterpret_cast<int4*>(V_sm)[i2] = vr1;
  }
#pragma unroll
  for (int j = 0; j < 3; ++j)
    *reinterpret_cast<int4*>(&Q_sm[qr_[j]][qc_[j] * 8]) = qn[j];
  __syncthreads();   // K/V visible to all waves (also drains Q0 writes)

  const float sc = 0.11180339887498949f;   // 80^-0.5

#define TILE_COMPUTE(toff)                                                     \
  do {                                                                         \
    f32x4 s[5];                                                                \
    _Pragma("unroll") for (int i = 0; i < 5; ++i)                              \
        s[i] = (f32x4){0.f, 0.f, 0.f, 0.f};                                    \
    __builtin_amdgcn_s_setprio(1);                                             \
    _Pragma("unroll") for (int ks = 0; ks < 3; ++ks) {                         \
      f16x8 bq = *reinterpret_cast<const f16x8*>(                              \
          &Q_sm[wave * 16 + ln][ks * 32 + g * 8]);                             \
      _Pragma("unroll") for (int mt = 0; mt < 5; ++mt) {                       \
        f16x8 ak = *reinterpret_cast<const f16x8*>(                            \
            &K_sm[mt * 16 + ln][ks * 32 + g * 8]);                             \
        s[mt] = __builtin_amdgcn_mfma_f32_16x16x32_f16(ak, bq, s[mt], 0, 0, 0);\
      }                                                                        \
    }                                                                          \
    __builtin_amdgcn_s_setprio(0);                                             \
    float mx = -1e30f;                                                         \
    _Pragma("unroll") for (int mt = 0; mt < 5; ++mt)                           \
      _Pragma("unroll") for (int r = 0; r < 4; ++r) {                          \
        const int t = mt * 16 + g * 4 + r;                                     \
        const float v = s[mt][r] * sc;                                         \
        s[mt][r] = v;                                                          \
        if (t < TT) mx = fmaxf(mx, v);                                         \
      }                                                                        \
    mx = fmaxf(mx, __shfl_xor(mx, 16));                                        \
    mx = fmaxf(mx, __shfl_xor(mx, 32));                                        \
    float e[5][4];                                                             \
    float sum = 0.f;                                                           \
    _Pragma("unroll") for (int mt = 0; mt < 5; ++mt)                           \
      _Pragma("unroll") for (int r = 0; r < 4; ++r) {                          \
        const int t = mt * 16 + g * 4 + r;                                     \
        float ev = 0.f;                                                        \
        if (t < TT) { ev = __expf(s[mt][r] - mx); sum += ev; }                 \
        e[mt][r] = ev;                                                         \
      }                                                                        \
    sum += __shfl_xor(sum, 16);                                                \
    sum += __shfl_xor(sum, 32);                                                \
    const float inv = 1.f / sum;                                               \
    _Pragma("unroll") for (int mt = 0; mt < 5; ++mt) {                         \
      f16x4 pv;                                                                \
      _Pragma("unroll") for (int r = 0; r < 4; ++r)                            \
        pv[r] = (half_t)(e[mt][r] * inv);                                      \
      *reinterpret_cast<f16x4*>(&Q_sm[wave * 16 + ln][mt * 16 + g * 4]) = pv;  \
    }                                                                          \
    f32x4 o[5];                                                                \
    _Pragma("unroll") for (int i = 0; i < 5; ++i)                              \
        o[i] = (f32x4){0.f, 0.f, 0.f, 0.f};                                    \
    __builtin_amdgcn_s_setprio(1);                                             \
    _Pragma("unroll") for (int ks = 0; ks < 3; ++ks) {                         \
      f16x8 bp = *reinterpret_cast<const f16x8*>(                              \
          &Q_sm[wave * 16 + ln][ks * 32 + g * 8]);                             \
      _Pragma("unroll") for (int mt = 0; mt < 5; ++mt) {                       \
        f16x8 av = *reinterpret_cast<const f16x8*>(                            \
            &V_sm[mt * 16 + ln][ks * 32 + g * 8]);                             \
        o[mt] = __builtin_amdgcn_mfma_f32_16x16x32_f16(av, bp, o[mt], 0, 0, 0);\
      }                                                                        \
    }                                                                          \
    __builtin_amdgcn_s_setprio(0);                                             \
    half_t* op = attn_ws +                                                     \
        ((long)(b * HWD + p0 + (toff) + wave * 16 + ln)) * CD + h * DH;        \
    _Pragma("unroll") for (int mt = 0; mt < 5; ++mt) {                         \
      f16x4 v4;                                                                \
      _Pragma("unroll") for (int r = 0; r < 4; ++r)                            \
        v4[r] = (half_t)o[mt][r];                                              \
      *reinterpret_cast<f16x4*>(&op[mt * 16 + g * 4]) = v4;                    \
    }                                                                          \
  } while (0)

#pragma unroll
  for (int tile = 0; tile < 8; ++tile) {
    // issue next tile's Q loads BEFORE compute; sched_barrier pins issue
    if (tile < 7) {
#pragma unroll
      for (int j = 0; j < 3; ++j) {
        qn[j] = make_int4(0, 0, 0, 0);
        if (qc_[j] < 10)
          qn[j] = *reinterpret_cast<const int4*>(
              qbase + (long)((tile + 1) * 128 + qr_[j]) * CD + qc_[j] * 8);
      }
      __builtin_amdgcn_sched_barrier(0);   // loads issued before compute
    }
    TILE_COMPUTE(tile * 128);
    if (tile < 7) {
      // stage Q tile+1 (wave-private; follows this wave's PV reads in the
      // in-order DS pipe, so no barrier needed)
#pragma unroll
      for (int j = 0; j < 3; ++j)
        *reinterpret_cast<int4*>(&Q_sm[qr_[j]][qc_[j] * 8]) = qn[j];
      asm volatile("s_waitcnt lgkmcnt(0)" ::: "memory");
      __builtin_amdgcn_sched_barrier(0);
    }
  }
#undef TILE_COMPUTE
}

// ---------------- launch ----------------
extern "C" void kernel_launch(void* const* d_in, const int* in_sizes, int n_in,
                              void* d_out, int out_size, void* d_ws, size_t ws_size,
                              hipStream_t stream) {
  const float* x   = (const float*)d_in[0];
  const float* ctx = (const float*)d_in[1];
  const float* Wq  = (const float*)d_in[2];
  const float* bq  = (const float*)d_in[3];
  const float* Wk  = (const float*)d_in[4];
  const float* bk  = (const float*)d_in[5];
  const float* Wv  = (const float*)d_in[6];
  const float* bv  = (const float*)d_in[7];
  const float* Wo  = (const float*)d_in[8];
  const float* bo  = (const float*)d_in[9];
  float* out = (float*)d_out;

  char* ws = (char*)d_ws;
  size_t off = 0;
  auto alloc = [&](size_t bytes) {
    void* p = ws + off;
    off += (bytes + 255) & ~(size_t)255;
    return p;
  };
  half_t* WqT  = (half_t*)alloc((size_t)CD * CD * 2);
  half_t* WkT  = (half_t*)alloc((size_t)CD * CTXD * 2);
  half_t* WvT  = (half_t*)alloc((size_t)CD * CTXD * 2);
  half_t* WoT  = (half_t*)alloc((size_t)CD * CD * 2);
  half_t* kws  = (half_t*)alloc((size_t)NB * NH * 80 * DP * 2);
  half_t* vTws = (half_t*)alloc((size_t)NB * NH * 80 * DP * 2);
  half_t* xt   = (half_t*)alloc((size_t)NB * HWD * CD * 2);
  half_t* q    = (half_t*)alloc((size_t)NB * HWD * CD * 2);
  half_t* attn = xt;   // xt dead after pgemm8<0>; alias

  // weight transposes (f32 -> f16)
  wtrans_kernel<<<dim3(CD / 64, CTXD / 64, 4), 256, 0, stream>>>(
      Wq, Wk, Wv, Wo, WqT, WkT, WvT, WoT);

  // K/V projection (+ pad zeroing)
  kv_kernel<<<dim3(CD / 64, NB, 2), 256, 0, stream>>>(ctx, WkT, WvT, bk, bv, kws, vTws);

  // x transpose + convert
  xpose_kernel<<<dim3(HWD / 64, CD / 64, NB), 256, 0, stream>>>(x, xt);

  // Q projection (256x128 tiles, phase-split schedule)
  pgemm8_kernel<0><<<(CD / 128) * ((NB * HWD) / 256), 512, 0, stream>>>(
      xt, WqT, bq, q);

  // fused attention (1024 px / block, 8-tile pipeline + setprio)
  attn_kernel<<<dim3(HWD / 1024, NH, NB), 512, 0, stream>>>(q, kws, vTws, attn);

  // O projection (256x128 tiles, phase-split schedule)
  pgemm8_kernel<1><<<(CD / 128) * ((NB * HWD) / 256), 512, 0, stream>>>(
      attn, WoT, bo, out);
}